// Round 1
// baseline (583.943 us; speedup 1.0000x reference)
//
#include <hip/hip_runtime.h>
#include <stdint.h>

typedef __attribute__((ext_vector_type(8))) short short8;
typedef __attribute__((ext_vector_type(4))) short short4v;
typedef __attribute__((ext_vector_type(4))) float f32x4;
typedef unsigned short u16;

#define DEV __device__ __forceinline__

constexpr int Bb = 2, Ss = 4096, Cc = 640, Hh = 8, Dd = 80;
constexpr int BS = Bb * Ss;          // 8192
constexpr int NQKV = 3 * Cc;         // 1920

DEV float bf2f(u16 u) { unsigned v = ((unsigned)u) << 16; float f; __builtin_memcpy(&f, &v, 4); return f; }
DEV u16 f2bf(float f) {
    unsigned u; __builtin_memcpy(&u, &f, 4);
    u += 0x7fffu + ((u >> 16) & 1u);
    return (u16)(u >> 16);
}

// ---------------------------------------------------------------------------
// Kernel A: convert inputs to bf16; transpose weights to [N][K]; concat bias.
// ---------------------------------------------------------------------------
__global__ void convert_kernel(const float* __restrict__ hs,
                               const float* __restrict__ Wq, const float* __restrict__ Wk,
                               const float* __restrict__ Wv, const float* __restrict__ Wo,
                               const float* __restrict__ bq, const float* __restrict__ bk,
                               const float* __restrict__ bv,
                               u16* __restrict__ Xb, u16* __restrict__ WTqkv,
                               u16* __restrict__ WTo, float* __restrict__ bcat)
{
    int tid = blockIdx.x * blockDim.x + threadIdx.x;
    int nthr = gridDim.x * blockDim.x;
    for (int i = tid; i < BS * Cc; i += nthr) Xb[i] = f2bf(hs[i]);
    for (int i = tid; i < NQKV * Cc; i += nthr) {
        int n = i / Cc, k = i % Cc;
        const float* W = (n < Cc) ? Wq : (n < 2 * Cc) ? Wk : Wv;
        int nn = (n >= 2 * Cc) ? n - 2 * Cc : (n >= Cc) ? n - Cc : n;
        WTqkv[i] = f2bf(W[(size_t)k * Cc + nn]);
    }
    for (int i = tid; i < Cc * Cc; i += nthr) {
        int n = i / Cc, k = i % Cc;
        WTo[i] = f2bf(Wo[(size_t)k * Cc + n]);
    }
    for (int i = tid; i < NQKV; i += nthr)
        bcat[i] = (i < Cc) ? bq[i] : (i < 2 * Cc) ? bk[i - Cc] : bv[i - 2 * Cc];
}

// ---------------------------------------------------------------------------
// Kernel B: bf16 GEMM  Out[m][n] = sum_k A[m][k] * Bt[n][k] + bias[n]
// 128x128 tile, 4 waves (2x2), 16x16x32 bf16 MFMA, bf16 output.
// ---------------------------------------------------------------------------
template <int N_TOTAL>
__global__ __launch_bounds__(256) void gemm_bf16(
    const u16* __restrict__ A, const u16* __restrict__ Bt,
    const float* __restrict__ bias, u16* __restrict__ Out, int K)
{
    constexpr int BKP = 40; // padded K-stride (elems): 80B rows, 2-way bank alias only
    __shared__ __align__(16) u16 As[128 * BKP];
    __shared__ __align__(16) u16 Bs[128 * BKP];

    const int mBase = blockIdx.x * 128;
    const int nBase = blockIdx.y * 128;
    const int t = threadIdx.x, lane = t & 63, w = t >> 6;
    const int wr = w >> 1, wc = w & 1;
    const int l15 = lane & 15, g = lane >> 4;

    f32x4 acc[4][4] = {};

    const int rowA = t >> 1;
    const int colA = (t & 1) * 16;

    for (int k0 = 0; k0 < K; k0 += 32) {
        const u16* pa = A + (size_t)(mBase + rowA) * K + k0 + colA;
        const u16* pb = Bt + (size_t)(nBase + rowA) * K + k0 + colA;
        short8 a0 = *(const short8*)pa;
        short8 a1 = *(const short8*)(pa + 8);
        short8 b0 = *(const short8*)pb;
        short8 b1 = *(const short8*)(pb + 8);
        *(short8*)&As[rowA * BKP + colA] = a0;
        *(short8*)&As[rowA * BKP + colA + 8] = a1;
        *(short8*)&Bs[rowA * BKP + colA] = b0;
        *(short8*)&Bs[rowA * BKP + colA + 8] = b1;
        __syncthreads();
        short8 af[4], bf[4];
#pragma unroll
        for (int i = 0; i < 4; i++) {
            af[i] = *(const short8*)&As[(wr * 64 + i * 16 + l15) * BKP + g * 8];
            bf[i] = *(const short8*)&Bs[(wc * 64 + i * 16 + l15) * BKP + g * 8];
        }
#pragma unroll
        for (int mi = 0; mi < 4; mi++)
#pragma unroll
            for (int ni = 0; ni < 4; ni++)
                acc[mi][ni] = __builtin_amdgcn_mfma_f32_16x16x32_bf16(af[mi], bf[ni], acc[mi][ni], 0, 0, 0);
        __syncthreads();
    }

#pragma unroll
    for (int mi = 0; mi < 4; mi++)
#pragma unroll
        for (int ni = 0; ni < 4; ni++) {
            int col = nBase + wc * 64 + ni * 16 + l15;
            float bb = bias[col];
#pragma unroll
            for (int r = 0; r < 4; r++) {
                int row = mBase + wr * 64 + mi * 16 + g * 4 + r;
                Out[(size_t)row * N_TOTAL + col] = f2bf(acc[mi][ni][r] + bb);
            }
        }
}

// ---------------------------------------------------------------------------
// Kernel C: flash attention. One block = 64 Q-rows of one (b,h). 4 waves.
// ---------------------------------------------------------------------------
constexpr int QSP = 104;  // Qs/Ks padded row stride (elems)
constexpr int VTP = 72;   // Vt padded row stride
constexpr int PWP = 72;   // per-wave P padded row stride

__global__ __launch_bounds__(256) void attn_kernel(
    const u16* __restrict__ QKV, u16* __restrict__ AOb)
{
    __shared__ __align__(16) u16 Qs[64 * QSP];
    __shared__ __align__(16) u16 Ks[64 * QSP];
    __shared__ __align__(16) u16 Vt[Dd * VTP];
    __shared__ __align__(16) u16 Pw[4][16 * PWP];

    const int qt = blockIdx.x;
    const int bh = blockIdx.y;
    const int b = bh >> 3, h = bh & 7;
    const int t = threadIdx.x, lane = t & 63, w = t >> 6;
    const int l15 = lane & 15, g = lane >> 4;

    const size_t rowBase = (size_t)b * Ss;
    const int qRow0 = qt * 64;

    // stage Q (scaled by 1/sqrt(D) * log2(e))
    const float qscale = 0.11180339887498949f * 1.4426950408889634f;
    for (int c = t; c < 64 * 20; c += 256) {
        int r = c / 20, c4 = (c % 20) * 4;
        const u16* src = QKV + (rowBase + qRow0 + r) * NQKV + h * Dd + c4;
        short4v v = *(const short4v*)src;
        short4v o;
#pragma unroll
        for (int j = 0; j < 4; j++) o[j] = (short)f2bf(bf2f((u16)v[j]) * qscale);
        *(short4v*)&Qs[r * QSP + c4] = o;
    }
    // zero Q,K pad columns [80,96)
    {
        int r = t >> 2, c4 = 80 + (t & 3) * 4;
        short4v z = 0;
        *(short4v*)&Qs[r * QSP + c4] = z;
        *(short4v*)&Ks[r * QSP + c4] = z;
    }
    __syncthreads();

    // hoist Q fragments (wave w owns q-rows w*16..w*16+15)
    short8 qf[3];
#pragma unroll
    for (int ks = 0; ks < 3; ks++)
        qf[ks] = *(const short8*)&Qs[(w * 16 + l15) * QSP + ks * 32 + g * 8];

    float mrow[4], lrow[4];
#pragma unroll
    for (int r = 0; r < 4; r++) { mrow[r] = -1e30f; lrow[r] = 0.f; }
    f32x4 oacc[5] = {};

    for (int kt = 0; kt < Ss / 64; ++kt) {
        __syncthreads();  // previous tile's LDS reads done
        // stage K and V tiles (V transposed)
        for (int c = t; c < 64 * 20; c += 256) {
            int r = c / 20, c4 = (c % 20) * 4;
            const u16* srcK = QKV + (rowBase + kt * 64 + r) * NQKV + Cc + h * Dd + c4;
            *(short4v*)&Ks[r * QSP + c4] = *(const short4v*)srcK;
            const u16* srcV = QKV + (rowBase + kt * 64 + r) * NQKV + 2 * Cc + h * Dd + c4;
            short4v vv = *(const short4v*)srcV;
#pragma unroll
            for (int j = 0; j < 4; j++) Vt[(c4 + j) * VTP + r] = (u16)vv[j];
        }
        __syncthreads();

        // S = Q K^T (scaled, log2 domain)
        f32x4 sfrag[4];
#pragma unroll
        for (int n = 0; n < 4; n++) {
            f32x4 a = {};
#pragma unroll
            for (int ks = 0; ks < 3; ks++) {
                short8 kf = *(const short8*)&Ks[(n * 16 + l15) * QSP + ks * 32 + g * 8];
                a = __builtin_amdgcn_mfma_f32_16x16x32_bf16(qf[ks], kf, a, 0, 0, 0);
            }
            sfrag[n] = a;
        }

        // online softmax (rows handled by this lane: g*4 + r)
        float alpha[4], tsum[4];
#pragma unroll
        for (int r = 0; r < 4; r++) {
            float v = fmaxf(fmaxf(sfrag[0][r], sfrag[1][r]), fmaxf(sfrag[2][r], sfrag[3][r]));
#pragma unroll
            for (int msk = 8; msk >= 1; msk >>= 1) v = fmaxf(v, __shfl_xor(v, msk, 64));
            float mnew = fmaxf(mrow[r], v);
            alpha[r] = exp2f(mrow[r] - mnew);
            mrow[r] = mnew;
            tsum[r] = 0.f;
        }
        u16 pbits[4][4];
#pragma unroll
        for (int n = 0; n < 4; n++)
#pragma unroll
            for (int r = 0; r < 4; r++) {
                float p = exp2f(sfrag[n][r] - mrow[r]);
                tsum[r] += p;
                pbits[n][r] = f2bf(p);
            }
#pragma unroll
        for (int r = 0; r < 4; r++) {
            float v = tsum[r];
#pragma unroll
            for (int msk = 8; msk >= 1; msk >>= 1) v += __shfl_xor(v, msk, 64);
            lrow[r] = lrow[r] * alpha[r] + v;
        }
#pragma unroll
        for (int n = 0; n < 5; n++)
#pragma unroll
            for (int r = 0; r < 4; r++) oacc[n][r] *= alpha[r];

        // transpose P via per-wave LDS, then PV
#pragma unroll
        for (int n = 0; n < 4; n++)
#pragma unroll
            for (int r = 0; r < 4; r++)
                Pw[w][(g * 4 + r) * PWP + n * 16 + l15] = pbits[n][r];
        // per-wave LDS region; in-wave DS ordering + compiler waitcnt suffice
#pragma unroll
        for (int ks = 0; ks < 2; ks++) {
            short8 pf = *(const short8*)&Pw[w][l15 * PWP + ks * 32 + g * 8];
#pragma unroll
            for (int n = 0; n < 5; n++) {
                short8 vf = *(const short8*)&Vt[(n * 16 + l15) * VTP + ks * 32 + g * 8];
                oacc[n] = __builtin_amdgcn_mfma_f32_16x16x32_bf16(pf, vf, oacc[n], 0, 0, 0);
            }
        }
    }

    // normalize + store
#pragma unroll
    for (int n = 0; n < 5; n++)
#pragma unroll
        for (int r = 0; r < 4; r++) {
            float o = oacc[n][r] / lrow[r];
            int row = qRow0 + w * 16 + g * 4 + r;
            int col = h * Dd + n * 16 + l15;
            AOb[(rowBase + row) * Cc + col] = f2bf(o);
        }
}

// ---------------------------------------------------------------------------
// Kernel D: O-projection + bias + residual, fp32 out.
// ---------------------------------------------------------------------------
__global__ __launch_bounds__(256) void gemm_oproj(
    const u16* __restrict__ A, const u16* __restrict__ Bt,
    const float* __restrict__ bias, const float* __restrict__ resid,
    float* __restrict__ Out, int K)
{
    constexpr int BKP = 40;
    __shared__ __align__(16) u16 As[128 * BKP];
    __shared__ __align__(16) u16 Bs[128 * BKP];

    const int mBase = blockIdx.x * 128;
    const int nBase = blockIdx.y * 128;
    const int t = threadIdx.x, lane = t & 63, w = t >> 6;
    const int wr = w >> 1, wc = w & 1;
    const int l15 = lane & 15, g = lane >> 4;

    f32x4 acc[4][4] = {};
    const int rowA = t >> 1;
    const int colA = (t & 1) * 16;

    for (int k0 = 0; k0 < K; k0 += 32) {
        const u16* pa = A + (size_t)(mBase + rowA) * K + k0 + colA;
        const u16* pb = Bt + (size_t)(nBase + rowA) * K + k0 + colA;
        short8 a0 = *(const short8*)pa;
        short8 a1 = *(const short8*)(pa + 8);
        short8 b0 = *(const short8*)pb;
        short8 b1 = *(const short8*)(pb + 8);
        *(short8*)&As[rowA * BKP + colA] = a0;
        *(short8*)&As[rowA * BKP + colA + 8] = a1;
        *(short8*)&Bs[rowA * BKP + colA] = b0;
        *(short8*)&Bs[rowA * BKP + colA + 8] = b1;
        __syncthreads();
        short8 af[4], bf[4];
#pragma unroll
        for (int i = 0; i < 4; i++) {
            af[i] = *(const short8*)&As[(wr * 64 + i * 16 + l15) * BKP + g * 8];
            bf[i] = *(const short8*)&Bs[(wc * 64 + i * 16 + l15) * BKP + g * 8];
        }
#pragma unroll
        for (int mi = 0; mi < 4; mi++)
#pragma unroll
            for (int ni = 0; ni < 4; ni++)
                acc[mi][ni] = __builtin_amdgcn_mfma_f32_16x16x32_bf16(af[mi], bf[ni], acc[mi][ni], 0, 0, 0);
        __syncthreads();
    }

#pragma unroll
    for (int mi = 0; mi < 4; mi++)
#pragma unroll
        for (int ni = 0; ni < 4; ni++) {
            int col = nBase + wc * 64 + ni * 16 + l15;
            float bb = bias[col];
#pragma unroll
            for (int r = 0; r < 4; r++) {
                int row = mBase + wr * 64 + mi * 16 + g * 4 + r;
                Out[(size_t)row * Cc + col] = acc[mi][ni][r] + bb + resid[(size_t)row * Cc + col];
            }
        }
}

// ---------------------------------------------------------------------------
extern "C" void kernel_launch(void* const* d_in, const int* in_sizes, int n_in,
                              void* d_out, int out_size, void* d_ws, size_t ws_size,
                              hipStream_t stream) {
    (void)in_sizes; (void)n_in; (void)out_size; (void)ws_size;
    const float* hs = (const float*)d_in[0];
    const float* Wq = (const float*)d_in[1];
    const float* bq = (const float*)d_in[2];
    const float* Wk = (const float*)d_in[3];
    const float* bk = (const float*)d_in[4];
    const float* Wv = (const float*)d_in[5];
    const float* bv = (const float*)d_in[6];
    const float* Wo = (const float*)d_in[7];
    const float* bo = (const float*)d_in[8];
    float* out = (float*)d_out;

    char* ws = (char*)d_ws;
    u16*   Xb    = (u16*)  (ws + 0);          // 8192*640*2   = 10,485,760
    u16*   WTqkv = (u16*)  (ws + 10485760);   // 1920*640*2   =  2,457,600
    u16*   WTo   = (u16*)  (ws + 12943360);   // 640*640*2    =    819,200
    float* bcat  = (float*)(ws + 13762560);   // 1920*4       =      7,680
    u16*   QKV   = (u16*)  (ws + 13770240);   // 8192*1920*2  = 31,457,280
    u16*   AOb   = (u16*)  (ws + 45227520);   // 8192*640*2   = 10,485,760

    convert_kernel<<<dim3(2048), dim3(256), 0, stream>>>(hs, Wq, Wk, Wv, Wo, bq, bk, bv,
                                                         Xb, WTqkv, WTo, bcat);
    gemm_bf16<NQKV><<<dim3(64, 15), dim3(256), 0, stream>>>(Xb, WTqkv, bcat, QKV, Cc);
    attn_kernel<<<dim3(64, 16), dim3(256), 0, stream>>>(QKV, AOb);
    gemm_oproj<<<dim3(64, 5), dim3(256), 0, stream>>>(AOb, WTo, bo, hs, out, Cc);
}

// Round 2
// 399.114 us; speedup vs baseline: 1.4631x; 1.4631x over previous
//
#include <hip/hip_runtime.h>
#include <stdint.h>

typedef __attribute__((ext_vector_type(8))) short short8;
typedef __attribute__((ext_vector_type(4))) short short4v;
typedef __attribute__((ext_vector_type(4))) float f32x4;
typedef unsigned short u16;

#define DEV __device__ __forceinline__

constexpr int Bb = 2, Ss = 4096, Cc = 640, Hh = 8, Dd = 80;
constexpr int BS = Bb * Ss;          // 8192
constexpr int NQKV = 3 * Cc;         // 1920

DEV float bf2f(u16 u) { unsigned v = ((unsigned)u) << 16; float f; __builtin_memcpy(&f, &v, 4); return f; }
DEV u16 f2bf(float f) {
    unsigned u; __builtin_memcpy(&u, &f, 4);
    u += 0x7fffu + ((u >> 16) & 1u);
    return (u16)(u >> 16);
}

// ---------------------------------------------------------------------------
// Kernel A: convert inputs to bf16; transpose weights to [N][K]; concat bias.
// ---------------------------------------------------------------------------
__global__ void convert_kernel(const float* __restrict__ hs,
                               const float* __restrict__ Wq, const float* __restrict__ Wk,
                               const float* __restrict__ Wv, const float* __restrict__ Wo,
                               const float* __restrict__ bq, const float* __restrict__ bk,
                               const float* __restrict__ bv,
                               u16* __restrict__ Xb, u16* __restrict__ WTqkv,
                               u16* __restrict__ WTo, float* __restrict__ bcat)
{
    int tid = blockIdx.x * blockDim.x + threadIdx.x;
    int nthr = gridDim.x * blockDim.x;
    for (int i = tid; i < BS * Cc; i += nthr) Xb[i] = f2bf(hs[i]);
    for (int i = tid; i < NQKV * Cc; i += nthr) {
        int n = i / Cc, k = i % Cc;
        const float* W = (n < Cc) ? Wq : (n < 2 * Cc) ? Wk : Wv;
        int nn = (n >= 2 * Cc) ? n - 2 * Cc : (n >= Cc) ? n - Cc : n;
        WTqkv[i] = f2bf(W[(size_t)k * Cc + nn]);
    }
    for (int i = tid; i < Cc * Cc; i += nthr) {
        int n = i / Cc, k = i % Cc;
        WTo[i] = f2bf(Wo[(size_t)k * Cc + n]);
    }
    for (int i = tid; i < NQKV; i += nthr)
        bcat[i] = (i < Cc) ? bq[i] : (i < 2 * Cc) ? bk[i - Cc] : bv[i - 2 * Cc];
}

// ---------------------------------------------------------------------------
// Kernel B: bf16 GEMM  Out[m][n] = sum_k A[m][k] * Bt[n][k] + bias[n]
// 128x128 tile, 4 waves (2x2), 16x16x32 bf16 MFMA, bf16 output.
// ---------------------------------------------------------------------------
template <int N_TOTAL>
__global__ __launch_bounds__(256) void gemm_bf16(
    const u16* __restrict__ A, const u16* __restrict__ Bt,
    const float* __restrict__ bias, u16* __restrict__ Out, int K)
{
    constexpr int BKP = 40; // padded K-stride (elems)
    __shared__ __align__(16) u16 As[128 * BKP];
    __shared__ __align__(16) u16 Bs[128 * BKP];

    const int mBase = blockIdx.x * 128;
    const int nBase = blockIdx.y * 128;
    const int t = threadIdx.x, lane = t & 63, w = t >> 6;
    const int wr = w >> 1, wc = w & 1;
    const int l15 = lane & 15, g = lane >> 4;

    f32x4 acc[4][4] = {};

    const int rowA = t >> 1;
    const int colA = (t & 1) * 16;

    for (int k0 = 0; k0 < K; k0 += 32) {
        const u16* pa = A + (size_t)(mBase + rowA) * K + k0 + colA;
        const u16* pb = Bt + (size_t)(nBase + rowA) * K + k0 + colA;
        short8 a0 = *(const short8*)pa;
        short8 a1 = *(const short8*)(pa + 8);
        short8 b0 = *(const short8*)pb;
        short8 b1 = *(const short8*)(pb + 8);
        *(short8*)&As[rowA * BKP + colA] = a0;
        *(short8*)&As[rowA * BKP + colA + 8] = a1;
        *(short8*)&Bs[rowA * BKP + colA] = b0;
        *(short8*)&Bs[rowA * BKP + colA + 8] = b1;
        __syncthreads();
        short8 af[4], bf[4];
#pragma unroll
        for (int i = 0; i < 4; i++) {
            af[i] = *(const short8*)&As[(wr * 64 + i * 16 + l15) * BKP + g * 8];
            bf[i] = *(const short8*)&Bs[(wc * 64 + i * 16 + l15) * BKP + g * 8];
        }
#pragma unroll
        for (int mi = 0; mi < 4; mi++)
#pragma unroll
            for (int ni = 0; ni < 4; ni++)
                acc[mi][ni] = __builtin_amdgcn_mfma_f32_16x16x32_bf16(af[mi], bf[ni], acc[mi][ni], 0, 0, 0);
        __syncthreads();
    }

#pragma unroll
    for (int mi = 0; mi < 4; mi++)
#pragma unroll
        for (int ni = 0; ni < 4; ni++) {
            int col = nBase + wc * 64 + ni * 16 + l15;
            float bb = bias[col];
#pragma unroll
            for (int r = 0; r < 4; r++) {
                int row = mBase + wr * 64 + mi * 16 + g * 4 + r;
                Out[(size_t)row * N_TOTAL + col] = f2bf(acc[mi][ni][r] + bb);
            }
        }
}

// ---------------------------------------------------------------------------
// Kernel C: flash attention. One block = 64 Q-rows of one (b,h). 4 waves.
// Conflict-free staging maps + async reg-staged K/V (T14) + exact defer-rescale.
// ---------------------------------------------------------------------------
constexpr int QSP = 104;  // Qs/Ks padded row stride (elems): 208B=52dw, 52%32=20 -> free frag reads
constexpr int VTP = 72;   // Vt padded row stride: 144B=36dw, 36%32=4 -> free frag reads
constexpr int PWP = 72;   // per-wave P padded row stride

__global__ __launch_bounds__(256) void attn_kernel(
    const u16* __restrict__ QKV, u16* __restrict__ AOb)
{
    __shared__ __align__(16) u16 Qs[64 * QSP];
    __shared__ __align__(16) u16 Ks[64 * QSP];
    __shared__ __align__(16) u16 Vt[80 * VTP];
    __shared__ __align__(16) u16 Pw[4][16 * PWP];

    const int qt = blockIdx.x;
    const int bh = blockIdx.y;
    const int b = bh >> 3, h = bh & 7;
    const int t = threadIdx.x, lane = t & 63, w = t >> 6;
    const int l15 = lane & 15, g = lane >> 4;

    const size_t rowBase = (size_t)b * Ss;
    const int qRow0 = qt * 64;
    constexpr int NT = Ss / 64;

    // ---- prologue: stage Q (scaled, scale = 1/sqrt(D) * log2(e)), tile-0 K/V ----
    const float qscale = 0.11180339887498949f * 1.4426950408889634f;

    // K/V tile 0 -> registers (issued first so latency overlaps Q staging)
    short8 kreg[3];
    short4v vreg[5];
    {
        const u16* kbase = QKV + (rowBase + 0 + lane) * NQKV + Cc + h * Dd;
#pragma unroll
        for (int j = 0; j < 3; j++) {
            int gi = w + 4 * j;
            if (gi < 10) kreg[j] = *(const short8*)(kbase + gi * 8);
        }
        const u16* vbase = QKV + (rowBase + 0 + lane) * NQKV + 2 * Cc + h * Dd + w * 20;
#pragma unroll
        for (int i = 0; i < 5; i++) vreg[i] = *(const short4v*)(vbase + i * 4);
    }

    // Q: lane = row, wave w handles granules {w, w+4, w+8}
    {
        const u16* qbase = QKV + (rowBase + qRow0 + lane) * NQKV + h * Dd;
#pragma unroll
        for (int j = 0; j < 3; j++) {
            int gi = w + 4 * j;
            if (gi < 10) {
                short8 v = *(const short8*)(qbase + gi * 8);
                short8 o;
#pragma unroll
                for (int e = 0; e < 8; e++) o[e] = (short)f2bf(bf2f((u16)v[e]) * qscale);
                *(short8*)&Qs[lane * QSP + gi * 8] = o;
            }
        }
        if (w >= 2) {  // zero pad granules 10,11 (d=80..95) of Q and K, once
            int gi = w + 8;
            short8 z = {};
            *(short8*)&Qs[lane * QSP + gi * 8] = z;
            *(short8*)&Ks[lane * QSP + gi * 8] = z;
        }
    }

    // write tile-0 K/V regs -> LDS
#pragma unroll
    for (int j = 0; j < 3; j++) {
        int gi = w + 4 * j;
        if (gi < 10) *(short8*)&Ks[lane * QSP + gi * 8] = kreg[j];
    }
    {
        int d0 = w * 20;
#pragma unroll
        for (int i = 0; i < 5; i++)
#pragma unroll
            for (int jj = 0; jj < 4; jj++)
                Vt[(d0 + i * 4 + jj) * VTP + lane] = (u16)vreg[i][jj];
    }
    __syncthreads();

    // hoist Q fragments (wave w owns q-rows w*16..w*16+15)
    short8 qf[3];
#pragma unroll
    for (int ks = 0; ks < 3; ks++)
        qf[ks] = *(const short8*)&Qs[(w * 16 + l15) * QSP + ks * 32 + g * 8];

    float mrow[4], lrow[4];
#pragma unroll
    for (int r = 0; r < 4; r++) { mrow[r] = -1e30f; lrow[r] = 0.f; }
    f32x4 oacc[5] = {};

    for (int kt = 0; kt < NT; ++kt) {
        const bool more = (kt + 1 < NT);
        // issue next tile's global loads early (latency hides under compute)
        if (more) {
            const u16* kbase = QKV + (rowBase + (kt + 1) * 64 + lane) * NQKV + Cc + h * Dd;
#pragma unroll
            for (int j = 0; j < 3; j++) {
                int gi = w + 4 * j;
                if (gi < 10) kreg[j] = *(const short8*)(kbase + gi * 8);
            }
            const u16* vbase = QKV + (rowBase + (kt + 1) * 64 + lane) * NQKV + 2 * Cc + h * Dd + w * 20;
#pragma unroll
            for (int i = 0; i < 5; i++) vreg[i] = *(const short4v*)(vbase + i * 4);
        }

        // S = Q K^T (scaled, log2 domain)
        f32x4 sfrag[4];
#pragma unroll
        for (int n = 0; n < 4; n++) {
            f32x4 a = {};
#pragma unroll
            for (int ks = 0; ks < 3; ks++) {
                short8 kf = *(const short8*)&Ks[(n * 16 + l15) * QSP + ks * 32 + g * 8];
                a = __builtin_amdgcn_mfma_f32_16x16x32_bf16(qf[ks], kf, a, 0, 0, 0);
            }
            sfrag[n] = a;
        }

        // online softmax (rows handled by this lane: q = g*4 + r)
        float vmax[4];
#pragma unroll
        for (int r = 0; r < 4; r++) {
            float v = fmaxf(fmaxf(sfrag[0][r], sfrag[1][r]), fmaxf(sfrag[2][r], sfrag[3][r]));
#pragma unroll
            for (int msk = 8; msk >= 1; msk >>= 1) v = fmaxf(v, __shfl_xor(v, msk, 64));
            vmax[r] = v;
        }
        int grow = 0;
#pragma unroll
        for (int r = 0; r < 4; r++) grow |= (vmax[r] > mrow[r]);
        if (__any(grow)) {  // exact skip: when no row grows, alpha==1 identically
#pragma unroll
            for (int r = 0; r < 4; r++) {
                float mnew = fmaxf(mrow[r], vmax[r]);
                float al = exp2f(mrow[r] - mnew);
                mrow[r] = mnew;
                lrow[r] *= al;
#pragma unroll
                for (int n = 0; n < 5; n++) oacc[n][r] *= al;
            }
        }
        float tsum[4] = {0.f, 0.f, 0.f, 0.f};
        u16 pbits[4][4];
#pragma unroll
        for (int n = 0; n < 4; n++)
#pragma unroll
            for (int r = 0; r < 4; r++) {
                float p = exp2f(sfrag[n][r] - mrow[r]);
                tsum[r] += p;
                pbits[n][r] = f2bf(p);
            }
#pragma unroll
        for (int r = 0; r < 4; r++) {
            float v = tsum[r];
#pragma unroll
            for (int msk = 8; msk >= 1; msk >>= 1) v += __shfl_xor(v, msk, 64);
            lrow[r] += v;
        }

        // transpose P via per-wave LDS, then PV
#pragma unroll
        for (int n = 0; n < 4; n++)
#pragma unroll
            for (int r = 0; r < 4; r++)
                Pw[w][(g * 4 + r) * PWP + n * 16 + l15] = pbits[n][r];
        // per-wave LDS region; in-wave DS ordering + compiler waitcnt suffice
#pragma unroll
        for (int ks = 0; ks < 2; ks++) {
            short8 pf = *(const short8*)&Pw[w][l15 * PWP + ks * 32 + g * 8];
#pragma unroll
            for (int n = 0; n < 5; n++) {
                short8 vf = *(const short8*)&Vt[(n * 16 + l15) * VTP + ks * 32 + g * 8];
                oacc[n] = __builtin_amdgcn_mfma_f32_16x16x32_bf16(pf, vf, oacc[n], 0, 0, 0);
            }
        }

        __syncthreads();   // all waves done reading Ks/Vt for tile kt
        if (more) {
            // write next tile (vmcnt drain happens here, after compute — T14)
#pragma unroll
            for (int j = 0; j < 3; j++) {
                int gi = w + 4 * j;
                if (gi < 10) *(short8*)&Ks[lane * QSP + gi * 8] = kreg[j];
            }
            int d0 = w * 20;
#pragma unroll
            for (int i = 0; i < 5; i++)
#pragma unroll
                for (int jj = 0; jj < 4; jj++)
                    Vt[(d0 + i * 4 + jj) * VTP + lane] = (u16)vreg[i][jj];
        }
        __syncthreads();   // next tile visible
    }

    // normalize + store
#pragma unroll
    for (int n = 0; n < 5; n++)
#pragma unroll
        for (int r = 0; r < 4; r++) {
            float o = oacc[n][r] / lrow[r];
            int row = qRow0 + w * 16 + g * 4 + r;
            int col = h * Dd + n * 16 + l15;
            AOb[(rowBase + row) * Cc + col] = f2bf(o);
        }
}

// ---------------------------------------------------------------------------
// Kernel D: O-projection + bias + residual, fp32 out.
// ---------------------------------------------------------------------------
__global__ __launch_bounds__(256) void gemm_oproj(
    const u16* __restrict__ A, const u16* __restrict__ Bt,
    const float* __restrict__ bias, const float* __restrict__ resid,
    float* __restrict__ Out, int K)
{
    constexpr int BKP = 40;
    __shared__ __align__(16) u16 As[128 * BKP];
    __shared__ __align__(16) u16 Bs[128 * BKP];

    const int mBase = blockIdx.x * 128;
    const int nBase = blockIdx.y * 128;
    const int t = threadIdx.x, lane = t & 63, w = t >> 6;
    const int wr = w >> 1, wc = w & 1;
    const int l15 = lane & 15, g = lane >> 4;

    f32x4 acc[4][4] = {};
    const int rowA = t >> 1;
    const int colA = (t & 1) * 16;

    for (int k0 = 0; k0 < K; k0 += 32) {
        const u16* pa = A + (size_t)(mBase + rowA) * K + k0 + colA;
        const u16* pb = Bt + (size_t)(nBase + rowA) * K + k0 + colA;
        short8 a0 = *(const short8*)pa;
        short8 a1 = *(const short8*)(pa + 8);
        short8 b0 = *(const short8*)pb;
        short8 b1 = *(const short8*)(pb + 8);
        *(short8*)&As[rowA * BKP + colA] = a0;
        *(short8*)&As[rowA * BKP + colA + 8] = a1;
        *(short8*)&Bs[rowA * BKP + colA] = b0;
        *(short8*)&Bs[rowA * BKP + colA + 8] = b1;
        __syncthreads();
        short8 af[4], bf[4];
#pragma unroll
        for (int i = 0; i < 4; i++) {
            af[i] = *(const short8*)&As[(wr * 64 + i * 16 + l15) * BKP + g * 8];
            bf[i] = *(const short8*)&Bs[(wc * 64 + i * 16 + l15) * BKP + g * 8];
        }
#pragma unroll
        for (int mi = 0; mi < 4; mi++)
#pragma unroll
            for (int ni = 0; ni < 4; ni++)
                acc[mi][ni] = __builtin_amdgcn_mfma_f32_16x16x32_bf16(af[mi], bf[ni], acc[mi][ni], 0, 0, 0);
        __syncthreads();
    }

#pragma unroll
    for (int mi = 0; mi < 4; mi++)
#pragma unroll
        for (int ni = 0; ni < 4; ni++) {
            int col = nBase + wc * 64 + ni * 16 + l15;
            float bb = bias[col];
#pragma unroll
            for (int r = 0; r < 4; r++) {
                int row = mBase + wr * 64 + mi * 16 + g * 4 + r;
                Out[(size_t)row * Cc + col] = acc[mi][ni][r] + bb + resid[(size_t)row * Cc + col];
            }
        }
}

// ---------------------------------------------------------------------------
extern "C" void kernel_launch(void* const* d_in, const int* in_sizes, int n_in,
                              void* d_out, int out_size, void* d_ws, size_t ws_size,
                              hipStream_t stream) {
    (void)in_sizes; (void)n_in; (void)out_size; (void)ws_size;
    const float* hs = (const float*)d_in[0];
    const float* Wq = (const float*)d_in[1];
    const float* bq = (const float*)d_in[2];
    const float* Wk = (const float*)d_in[3];
    const float* bk = (const float*)d_in[4];
    const float* Wv = (const float*)d_in[5];
    const float* bv = (const float*)d_in[6];
    const float* Wo = (const float*)d_in[7];
    const float* bo = (const float*)d_in[8];
    float* out = (float*)d_out;

    char* ws = (char*)d_ws;
    u16*   Xb    = (u16*)  (ws + 0);          // 8192*640*2   = 10,485,760
    u16*   WTqkv = (u16*)  (ws + 10485760);   // 1920*640*2   =  2,457,600
    u16*   WTo   = (u16*)  (ws + 12943360);   // 640*640*2    =    819,200
    float* bcat  = (float*)(ws + 13762560);   // 1920*4       =      7,680
    u16*   QKV   = (u16*)  (ws + 13770240);   // 8192*1920*2  = 31,457,280
    u16*   AOb   = (u16*)  (ws + 45227520);   // 8192*640*2   = 10,485,760

    convert_kernel<<<dim3(2048), dim3(256), 0, stream>>>(hs, Wq, Wk, Wv, Wo, bq, bk, bv,
                                                         Xb, WTqkv, WTo, bcat);
    gemm_bf16<NQKV><<<dim3(64, 15), dim3(256), 0, stream>>>(Xb, WTqkv, bcat, QKV, Cc);
    attn_kernel<<<dim3(64, 16), dim3(256), 0, stream>>>(QKV, AOb);
    gemm_oproj<<<dim3(64, 5), dim3(256), 0, stream>>>(AOb, WTo, bo, hs, out, Cc);
}

// Round 3
// 238.485 us; speedup vs baseline: 2.4486x; 1.6735x over previous
//
#include <hip/hip_runtime.h>
#include <hip/hip_bf16.h>
#include <stdint.h>

typedef __attribute__((ext_vector_type(8))) short short8;
typedef __attribute__((ext_vector_type(4))) short short4v;
typedef __attribute__((ext_vector_type(4))) float f32x4;
typedef __attribute__((ext_vector_type(16))) float f32x16;
typedef unsigned short u16;
typedef unsigned int u32;

#define DEV __device__ __forceinline__

constexpr int Bb = 2, Ss = 4096, Cc = 640, Hh = 8, Dd = 80;
constexpr int BS = Bb * Ss;          // 8192
constexpr int NQKV = 3 * Cc;         // 1920

DEV float bf2f(u16 u) { unsigned v = ((unsigned)u) << 16; float f; __builtin_memcpy(&f, &v, 4); return f; }
DEV u16 f2bf(float f) {
    unsigned u; __builtin_memcpy(&u, &f, 4);
    u += 0x7fffu + ((u >> 16) & 1u);
    return (u16)(u >> 16);
}
DEV u32 packbf2(float a, float b) {
    float2 f2; f2.x = a; f2.y = b;
    __hip_bfloat162 h2 = __float22bfloat162_rn(f2);
    u32 r; __builtin_memcpy(&r, &h2, 4);
    return r;
}

// ---------------------------------------------------------------------------
// Kernel A: convert to bf16; transpose weights to [N][K]; concat bias.
// Q-part of Wq/bq pre-scaled by (1/sqrt(D))*log2(e) for log2-domain softmax.
// ---------------------------------------------------------------------------
__global__ void convert_kernel(const float* __restrict__ hs,
                               const float* __restrict__ Wq, const float* __restrict__ Wk,
                               const float* __restrict__ Wv, const float* __restrict__ Wo,
                               const float* __restrict__ bq, const float* __restrict__ bk,
                               const float* __restrict__ bv,
                               u16* __restrict__ Xb, u16* __restrict__ WTqkv,
                               u16* __restrict__ WTo, float* __restrict__ bcat)
{
    const float QS = 0.11180339887498949f * 1.4426950408889634f;
    int tid = blockIdx.x * blockDim.x + threadIdx.x;
    int nthr = gridDim.x * blockDim.x;
    for (int i = tid; i < BS * Cc; i += nthr) Xb[i] = f2bf(hs[i]);
    for (int i = tid; i < NQKV * Cc; i += nthr) {
        int n = i / Cc, k = i % Cc;
        const float* W = (n < Cc) ? Wq : (n < 2 * Cc) ? Wk : Wv;
        int nn = (n >= 2 * Cc) ? n - 2 * Cc : (n >= Cc) ? n - Cc : n;
        float sc = (n < Cc) ? QS : 1.0f;
        WTqkv[i] = f2bf(W[(size_t)k * Cc + nn] * sc);
    }
    for (int i = tid; i < Cc * Cc; i += nthr) {
        int n = i / Cc, k = i % Cc;
        WTo[i] = f2bf(Wo[(size_t)k * Cc + n]);
    }
    for (int i = tid; i < NQKV; i += nthr) {
        float v = (i < Cc) ? bq[i] * QS : (i < 2 * Cc) ? bk[i - Cc] : bv[i - 2 * Cc];
        bcat[i] = v;
    }
}

// ---------------------------------------------------------------------------
// Kernel B: bf16 GEMM  Out[m][n] = sum_k A[m][k] * Bt[n][k] + bias[n]
// ---------------------------------------------------------------------------
template <int N_TOTAL>
__global__ __launch_bounds__(256) void gemm_bf16(
    const u16* __restrict__ A, const u16* __restrict__ Bt,
    const float* __restrict__ bias, u16* __restrict__ Out, int K)
{
    constexpr int BKP = 40;
    __shared__ __align__(16) u16 As[128 * BKP];
    __shared__ __align__(16) u16 Bs[128 * BKP];

    const int mBase = blockIdx.x * 128;
    const int nBase = blockIdx.y * 128;
    const int t = threadIdx.x, lane = t & 63, w = t >> 6;
    const int wr = w >> 1, wc = w & 1;
    const int l15 = lane & 15, g = lane >> 4;

    f32x4 acc[4][4] = {};
    const int rowA = t >> 1;
    const int colA = (t & 1) * 16;

    for (int k0 = 0; k0 < K; k0 += 32) {
        const u16* pa = A + (size_t)(mBase + rowA) * K + k0 + colA;
        const u16* pb = Bt + (size_t)(nBase + rowA) * K + k0 + colA;
        short8 a0 = *(const short8*)pa;
        short8 a1 = *(const short8*)(pa + 8);
        short8 b0 = *(const short8*)pb;
        short8 b1 = *(const short8*)(pb + 8);
        *(short8*)&As[rowA * BKP + colA] = a0;
        *(short8*)&As[rowA * BKP + colA + 8] = a1;
        *(short8*)&Bs[rowA * BKP + colA] = b0;
        *(short8*)&Bs[rowA * BKP + colA + 8] = b1;
        __syncthreads();
        short8 af[4], bf[4];
#pragma unroll
        for (int i = 0; i < 4; i++) {
            af[i] = *(const short8*)&As[(wr * 64 + i * 16 + l15) * BKP + g * 8];
            bf[i] = *(const short8*)&Bs[(wc * 64 + i * 16 + l15) * BKP + g * 8];
        }
#pragma unroll
        for (int mi = 0; mi < 4; mi++)
#pragma unroll
            for (int ni = 0; ni < 4; ni++)
                acc[mi][ni] = __builtin_amdgcn_mfma_f32_16x16x32_bf16(af[mi], bf[ni], acc[mi][ni], 0, 0, 0);
        __syncthreads();
    }

#pragma unroll
    for (int mi = 0; mi < 4; mi++)
#pragma unroll
        for (int ni = 0; ni < 4; ni++) {
            int col = nBase + wc * 64 + ni * 16 + l15;
            float bb = bias[col];
#pragma unroll
            for (int r = 0; r < 4; r++) {
                int row = mBase + wr * 64 + mi * 16 + g * 4 + r;
                Out[(size_t)row * N_TOTAL + col] = f2bf(acc[mi][ni][r] + bb);
            }
        }
}

// ---------------------------------------------------------------------------
// Kernel C: flash attention, 32x32x16 MFMA, swapped operands (S^T, O^T).
// Block = 128 q-rows of one (b,h); 4 waves x 32 q-rows. KV tile = 64.
// Softmax lane-local (q = lane&31); P stays in registers (cvt_pk + shfl).
// ---------------------------------------------------------------------------
constexpr int KSP = 88;   // Ks row stride (u16): 44 dw, 44%32=12 -> spread starts
constexpr int VTP = 72;   // Vt row stride (u16): 36 dw, 36%32=4
constexpr int OBP = 88;   // Ob row stride

__global__ __launch_bounds__(256) void attn_kernel(
    const u16* __restrict__ QKV, u16* __restrict__ AOb)
{
    __shared__ __align__(16) char smem[25088];
    u16* Ks = (u16*)smem;              // [64][88]  = 11264 B
    u16* Vt = (u16*)(smem + 11264);    // [96][72]  = 13824 B
    u16* Ob = (u16*)smem;              // [128][88] = 22528 B (overlay, post-loop)

    const int qt = blockIdx.x;         // 0..31
    const int bh = blockIdx.y;
    const int b = bh >> 3, h = bh & 7;
    const int t = threadIdx.x, lane = t & 63, w = t >> 6;
    const int l31 = lane & 31, e = lane >> 5;

    const size_t rowBase = (size_t)b * Ss;
    const int q0 = qt * 128;
    constexpr int NT = Ss / 64;

    // zero Vt pad rows [80,96) once
    {
        u32* z = (u32*)(Vt + 80 * VTP);
        for (int i = t; i < 16 * VTP / 2; i += 256) z[i] = 0;
    }

    // Q fragments direct from global (Wq pre-scaled): B-frag[k=d][col=q]
    short8 qB[5];
    {
        const u16* qp = QKV + (rowBase + q0 + w * 32 + l31) * NQKV + h * Dd + e * 8;
#pragma unroll
        for (int ks = 0; ks < 5; ks++) qB[ks] = *(const short8*)(qp + ks * 16);
    }

    short8 kreg[3];
    short4v vreg[5];

    auto loadKV = [&](int kt) {
        const u16* kb = QKV + (rowBase + kt * 64 + lane) * NQKV + Cc + h * Dd;
#pragma unroll
        for (int j = 0; j < 3; j++) {
            int gi = w + 4 * j;
            if (gi < 10) kreg[j] = *(const short8*)(kb + gi * 8);
        }
        const u16* vb = QKV + (rowBase + kt * 64 + lane) * NQKV + 2 * Cc + h * Dd + w * 20;
#pragma unroll
        for (int i = 0; i < 5; i++) vreg[i] = *(const short4v*)(vb + i * 4);
    };
    auto writeKV = [&]() {
#pragma unroll
        for (int j = 0; j < 3; j++) {
            int gi = w + 4 * j;
            if (gi < 10) *(short8*)&Ks[lane * KSP + gi * 8] = kreg[j];
        }
#pragma unroll
        for (int i = 0; i < 5; i++)
#pragma unroll
            for (int jj = 0; jj < 4; jj++)
                Vt[(w * 20 + i * 4 + jj) * VTP + lane] = (u16)vreg[i][jj];
    };

    loadKV(0);
    writeKV();
    __syncthreads();

    float mrow = -1e30f, lrow = 0.f;
    f32x16 oacc[3] = {};

    for (int kt = 0; kt < NT; ++kt) {
        const bool more = (kt + 1 < NT);
        if (more) loadKV(kt + 1);

        // S^T[kv][q] = K Q^T : A = K rows (kv), B = Q cols (q = l31)
        f32x16 s[2];
#pragma unroll
        for (int n = 0; n < 2; n++) {
            f32x16 a = {};
#pragma unroll
            for (int ks = 0; ks < 5; ks++) {
                short8 kf = *(const short8*)&Ks[(n * 32 + l31) * KSP + ks * 16 + e * 8];
                a = __builtin_amdgcn_mfma_f32_32x32x16_bf16(kf, qB[ks], a, 0, 0, 0);
            }
            s[n] = a;
        }

        // lane-local softmax for q = q0 + w*32 + l31 (log2 domain)
        float tm[16];
#pragma unroll
        for (int i = 0; i < 16; i++) tm[i] = fmaxf(s[0][i], s[1][i]);
#pragma unroll
        for (int st = 8; st >= 1; st >>= 1)
#pragma unroll
            for (int i = 0; i < st; i++) tm[i] = fmaxf(tm[i], tm[i + st]);
        float vm = tm[0];
        vm = fmaxf(vm, __shfl_xor(vm, 32, 64));

        if (__any(vm > mrow)) {   // exact skip: alpha==1 when no growth
            float mnew = fmaxf(mrow, vm);
            float al = __builtin_amdgcn_exp2f(mrow - mnew);
            mrow = mnew;
            lrow *= al;
#pragma unroll
            for (int n = 0; n < 3; n++)
#pragma unroll
                for (int r = 0; r < 16; r++) oacc[n][r] *= al;
        }

        // p = exp2(s - m), pack pairs (consecutive local kv) to bf16 dwords
        u32 pd[2][8];
        float ts0 = 0.f, ts1 = 0.f;
#pragma unroll
        for (int n = 0; n < 2; n++)
#pragma unroll
            for (int m = 0; m < 8; m++) {
                float pa = __builtin_amdgcn_exp2f(s[n][2 * m] - mrow);
                float pb = __builtin_amdgcn_exp2f(s[n][2 * m + 1] - mrow);
                if (n == 0) ts0 += pa + pb; else ts1 += pa + pb;
                pd[n][m] = packbf2(pa, pb);
            }
        float ts = ts0 + ts1;
        ts += __shfl_xor(ts, 32, 64);
        lrow += ts;

        // PV: O^T[d][q] += V^T[d][kv] * P^T[kv][q]; B-frag assembled in-reg
#pragma unroll
        for (int ks = 0; ks < 4; ks++) {
            const int n = ks >> 1, bb = ks & 1;
            u32 x0 = pd[n][4 * bb + 0], x1 = pd[n][4 * bb + 1];
            u32 x2 = pd[n][4 * bb + 2], x3 = pd[n][4 * bb + 3];
            u32 s0 = (u32)__shfl_xor((int)x0, 32, 64);
            u32 s1 = (u32)__shfl_xor((int)x1, 32, 64);
            u32 s2 = (u32)__shfl_xor((int)x2, 32, 64);
            u32 s3 = (u32)__shfl_xor((int)x3, 32, 64);
            union { u32 u[4]; short8 v; } pB;
            pB.u[0] = e ? s2 : x0;
            pB.u[1] = e ? s3 : x1;
            pB.u[2] = e ? x2 : s0;
            pB.u[3] = e ? x3 : s1;
#pragma unroll
            for (int n2 = 0; n2 < 3; n2++) {
                short8 vf = *(const short8*)&Vt[(n2 * 32 + l31) * VTP + ks * 16 + e * 8];
                oacc[n2] = __builtin_amdgcn_mfma_f32_32x32x16_bf16(vf, pB.v, oacc[n2], 0, 0, 0);
            }
        }

        __syncthreads();          // all waves done reading Ks/Vt
        if (more) writeKV();
        __syncthreads();          // next tile visible
    }

    // normalize, pack, dump O^T -> Ob (row = q-local, col = d), then coalesce out
    float rl = 1.0f / lrow;
#pragma unroll
    for (int n = 0; n < 3; n++)
#pragma unroll
        for (int r = 0; r < 16; r += 2) {
            if (n == 2 && r >= 8) continue;           // d >= 80
            int dloc = n * 32 + (r & 3) + 8 * (r >> 2) + 4 * e;
            u32 pk = packbf2(oacc[n][r] * rl, oacc[n][r + 1] * rl);
            *(u32*)&Ob[(w * 32 + l31) * OBP + dloc] = pk;
        }
    __syncthreads();

#pragma unroll
    for (int i = 0; i < 5; i++) {
        int gidx = i * 256 + t;                       // 0..1279
        int row = gidx / 10, gi = gidx % 10;
        short8 v = *(const short8*)&Ob[row * OBP + gi * 8];
        *(short8*)(AOb + (rowBase + q0 + row) * Cc + h * Dd + gi * 8) = v;
    }
}

// ---------------------------------------------------------------------------
// Kernel D: O-projection + bias + residual, fp32 out.
// ---------------------------------------------------------------------------
__global__ __launch_bounds__(256) void gemm_oproj(
    const u16* __restrict__ A, const u16* __restrict__ Bt,
    const float* __restrict__ bias, const float* __restrict__ resid,
    float* __restrict__ Out, int K)
{
    constexpr int BKP = 40;
    __shared__ __align__(16) u16 As[128 * BKP];
    __shared__ __align__(16) u16 Bs[128 * BKP];

    const int mBase = blockIdx.x * 128;
    const int nBase = blockIdx.y * 128;
    const int t = threadIdx.x, lane = t & 63, w = t >> 6;
    const int wr = w >> 1, wc = w & 1;
    const int l15 = lane & 15, g = lane >> 4;

    f32x4 acc[4][4] = {};
    const int rowA = t >> 1;
    const int colA = (t & 1) * 16;

    for (int k0 = 0; k0 < K; k0 += 32) {
        const u16* pa = A + (size_t)(mBase + rowA) * K + k0 + colA;
        const u16* pb = Bt + (size_t)(nBase + rowA) * K + k0 + colA;
        short8 a0 = *(const short8*)pa;
        short8 a1 = *(const short8*)(pa + 8);
        short8 b0 = *(const short8*)pb;
        short8 b1 = *(const short8*)(pb + 8);
        *(short8*)&As[rowA * BKP + colA] = a0;
        *(short8*)&As[rowA * BKP + colA + 8] = a1;
        *(short8*)&Bs[rowA * BKP + colA] = b0;
        *(short8*)&Bs[rowA * BKP + colA + 8] = b1;
        __syncthreads();
        short8 af[4], bf[4];
#pragma unroll
        for (int i = 0; i < 4; i++) {
            af[i] = *(const short8*)&As[(wr * 64 + i * 16 + l15) * BKP + g * 8];
            bf[i] = *(const short8*)&Bs[(wc * 64 + i * 16 + l15) * BKP + g * 8];
        }
#pragma unroll
        for (int mi = 0; mi < 4; mi++)
#pragma unroll
            for (int ni = 0; ni < 4; ni++)
                acc[mi][ni] = __builtin_amdgcn_mfma_f32_16x16x32_bf16(af[mi], bf[ni], acc[mi][ni], 0, 0, 0);
        __syncthreads();
    }

#pragma unroll
    for (int mi = 0; mi < 4; mi++)
#pragma unroll
        for (int ni = 0; ni < 4; ni++) {
            int col = nBase + wc * 64 + ni * 16 + l15;
            float bb = bias[col];
#pragma unroll
            for (int r = 0; r < 4; r++) {
                int row = mBase + wr * 64 + mi * 16 + g * 4 + r;
                Out[(size_t)row * Cc + col] = acc[mi][ni][r] + bb + resid[(size_t)row * Cc + col];
            }
        }
}

// ---------------------------------------------------------------------------
extern "C" void kernel_launch(void* const* d_in, const int* in_sizes, int n_in,
                              void* d_out, int out_size, void* d_ws, size_t ws_size,
                              hipStream_t stream) {
    (void)in_sizes; (void)n_in; (void)out_size; (void)ws_size;
    const float* hs = (const float*)d_in[0];
    const float* Wq = (const float*)d_in[1];
    const float* bq = (const float*)d_in[2];
    const float* Wk = (const float*)d_in[3];
    const float* bk = (const float*)d_in[4];
    const float* Wv = (const float*)d_in[5];
    const float* bv = (const float*)d_in[6];
    const float* Wo = (const float*)d_in[7];
    const float* bo = (const float*)d_in[8];
    float* out = (float*)d_out;

    char* ws = (char*)d_ws;
    u16*   Xb    = (u16*)  (ws + 0);          // 8192*640*2   = 10,485,760
    u16*   WTqkv = (u16*)  (ws + 10485760);   // 1920*640*2   =  2,457,600
    u16*   WTo   = (u16*)  (ws + 12943360);   // 640*640*2    =    819,200
    float* bcat  = (float*)(ws + 13762560);   // 1920*4       =      7,680
    u16*   QKV   = (u16*)  (ws + 13770240);   // 8192*1920*2  = 31,457,280
    u16*   AOb   = (u16*)  (ws + 45227520);   // 8192*640*2   = 10,485,760

    convert_kernel<<<dim3(2048), dim3(256), 0, stream>>>(hs, Wq, Wk, Wv, Wo, bq, bk, bv,
                                                         Xb, WTqkv, WTo, bcat);
    gemm_bf16<NQKV><<<dim3(64, 15), dim3(256), 0, stream>>>(Xb, WTqkv, bcat, QKV, Cc);
    attn_kernel<<<dim3(32, 16), dim3(256), 0, stream>>>(QKV, AOb);
    gemm_oproj<<<dim3(64, 5), dim3(256), 0, stream>>>(AOb, WTo, bo, hs, out, Cc);
}

// Round 5
// 236.599 us; speedup vs baseline: 2.4681x; 1.0080x over previous
//
#include <hip/hip_runtime.h>
#include <hip/hip_bf16.h>
#include <stdint.h>

typedef __attribute__((ext_vector_type(8))) short short8;
typedef __attribute__((ext_vector_type(4))) short short4v;
typedef __attribute__((ext_vector_type(4))) float f32x4;
typedef __attribute__((ext_vector_type(16))) float f32x16;
typedef unsigned short u16;
typedef unsigned int u32;

#define DEV __device__ __forceinline__

constexpr int Bb = 2, Ss = 4096, Cc = 640, Hh = 8, Dd = 80;
constexpr int BS = Bb * Ss;          // 8192
constexpr int NQKV = 3 * Cc;         // 1920

DEV float bf2f(u16 u) { unsigned v = ((unsigned)u) << 16; float f; __builtin_memcpy(&f, &v, 4); return f; }
DEV u16 f2bf(float f) {
    unsigned u; __builtin_memcpy(&u, &f, 4);
    u += 0x7fffu + ((u >> 16) & 1u);
    return (u16)(u >> 16);
}
DEV u32 packbf2(float a, float b) {
    float2 f2; f2.x = a; f2.y = b;
    __hip_bfloat162 h2 = __float22bfloat162_rn(f2);
    u32 r; __builtin_memcpy(&r, &h2, 4);
    return r;
}

// permlane32_swap: a' = lane<32 ? a : b[l-32];  b' = lane<32 ? a[l+32] : b
DEV void pswapf(float &a, float &b) {
#if __has_builtin(__builtin_amdgcn_permlane32_swap)
    auto r = __builtin_amdgcn_permlane32_swap(__float_as_int(a), __float_as_int(b), false, false);
    a = __int_as_float(r[0]); b = __int_as_float(r[1]);
#else
    float sa = __shfl_xor(a, 32, 64), sb = __shfl_xor(b, 32, 64);
    bool hi = (threadIdx.x & 32) != 0;
    float na = hi ? sb : a, nb = hi ? b : sa;
    a = na; b = nb;
#endif
}
DEV void pswap2(u32 &a, u32 &b) {
#if __has_builtin(__builtin_amdgcn_permlane32_swap)
    auto r = __builtin_amdgcn_permlane32_swap((int)a, (int)b, false, false);
    a = (u32)r[0]; b = (u32)r[1];
#else
    u32 sa = (u32)__shfl_xor((int)a, 32, 64), sb = (u32)__shfl_xor((int)b, 32, 64);
    bool hi = (threadIdx.x & 32) != 0;
    u32 na = hi ? sb : a, nb = hi ? b : sa;
    a = na; b = nb;
#endif
}

#define GLD16(gp, lp) __builtin_amdgcn_global_load_lds( \
    (const __attribute__((address_space(1))) void*)(gp), \
    (__attribute__((address_space(3))) void*)(lp), 16, 0, 0)

// ---------------------------------------------------------------------------
// Kernel A: convert to bf16; transpose weights to [N][K]; concat bias.
// Q-part of Wq/bq pre-scaled by (1/sqrt(D))*log2(e).
// ---------------------------------------------------------------------------
__global__ void convert_kernel(const float* __restrict__ hs,
                               const float* __restrict__ Wq, const float* __restrict__ Wk,
                               const float* __restrict__ Wv, const float* __restrict__ Wo,
                               const float* __restrict__ bq, const float* __restrict__ bk,
                               const float* __restrict__ bv,
                               u16* __restrict__ Xb, u16* __restrict__ WTqkv,
                               u16* __restrict__ WTo, float* __restrict__ bcat)
{
    const float QS = 0.11180339887498949f * 1.4426950408889634f;
    int tid = blockIdx.x * blockDim.x + threadIdx.x;
    int nthr = gridDim.x * blockDim.x;
    for (int i = tid; i < BS * Cc; i += nthr) Xb[i] = f2bf(hs[i]);
    for (int i = tid; i < NQKV * Cc; i += nthr) {
        int n = i / Cc, k = i % Cc;
        const float* W = (n < Cc) ? Wq : (n < 2 * Cc) ? Wk : Wv;
        int nn = (n >= 2 * Cc) ? n - 2 * Cc : (n >= Cc) ? n - Cc : n;
        float sc = (n < Cc) ? QS : 1.0f;
        WTqkv[i] = f2bf(W[(size_t)k * Cc + nn] * sc);
    }
    for (int i = tid; i < Cc * Cc; i += nthr) {
        int n = i / Cc, k = i % Cc;
        WTo[i] = f2bf(Wo[(size_t)k * Cc + n]);
    }
    for (int i = tid; i < NQKV; i += nthr) {
        float v = (i < Cc) ? bq[i] * QS : (i < 2 * Cc) ? bk[i - Cc] : bv[i - 2 * Cc];
        bcat[i] = v;
    }
}

// ---------------------------------------------------------------------------
// Kernel B: bf16 GEMM  Out[m][n] = sum_k A[m][k] * Bt[n][k] + bias[n]
// ---------------------------------------------------------------------------
template <int N_TOTAL>
__global__ __launch_bounds__(256) void gemm_bf16(
    const u16* __restrict__ A, const u16* __restrict__ Bt,
    const float* __restrict__ bias, u16* __restrict__ Out, int K)
{
    constexpr int BKP = 40;
    __shared__ __align__(16) u16 As[128 * BKP];
    __shared__ __align__(16) u16 Bs[128 * BKP];

    const int mBase = blockIdx.x * 128;
    const int nBase = blockIdx.y * 128;
    const int t = threadIdx.x, lane = t & 63, w = t >> 6;
    const int wr = w >> 1, wc = w & 1;
    const int l15 = lane & 15, g = lane >> 4;

    f32x4 acc[4][4] = {};
    const int rowA = t >> 1;
    const int colA = (t & 1) * 16;

    for (int k0 = 0; k0 < K; k0 += 32) {
        const u16* pa = A + (size_t)(mBase + rowA) * K + k0 + colA;
        const u16* pb = Bt + (size_t)(nBase + rowA) * K + k0 + colA;
        short8 a0 = *(const short8*)pa;
        short8 a1 = *(const short8*)(pa + 8);
        short8 b0 = *(const short8*)pb;
        short8 b1 = *(const short8*)(pb + 8);
        *(short8*)&As[rowA * BKP + colA] = a0;
        *(short8*)&As[rowA * BKP + colA + 8] = a1;
        *(short8*)&Bs[rowA * BKP + colA] = b0;
        *(short8*)&Bs[rowA * BKP + colA + 8] = b1;
        __syncthreads();
        short8 af[4], bf[4];
#pragma unroll
        for (int i = 0; i < 4; i++) {
            af[i] = *(const short8*)&As[(wr * 64 + i * 16 + l15) * BKP + g * 8];
            bf[i] = *(const short8*)&Bs[(wc * 64 + i * 16 + l15) * BKP + g * 8];
        }
#pragma unroll
        for (int mi = 0; mi < 4; mi++)
#pragma unroll
            for (int ni = 0; ni < 4; ni++)
                acc[mi][ni] = __builtin_amdgcn_mfma_f32_16x16x32_bf16(af[mi], bf[ni], acc[mi][ni], 0, 0, 0);
        __syncthreads();
    }

#pragma unroll
    for (int mi = 0; mi < 4; mi++)
#pragma unroll
        for (int ni = 0; ni < 4; ni++) {
            int col = nBase + wc * 64 + ni * 16 + l15;
            float bb = bias[col];
#pragma unroll
            for (int r = 0; r < 4; r++) {
                int row = mBase + wr * 64 + mi * 16 + g * 4 + r;
                Out[(size_t)row * N_TOTAL + col] = f2bf(acc[mi][ni][r] + bb);
            }
        }
}

// ---------------------------------------------------------------------------
// Kernel B2: transpose V part of QKV -> VTg[b*8+h][d][s]  ([16][80][4096] bf16)
// ---------------------------------------------------------------------------
__global__ __launch_bounds__(256) void vtrans_kernel(const u16* __restrict__ QKV,
                                                     u16* __restrict__ VTg)
{
    __shared__ __align__(16) u16 T[80][72];
    const int st = blockIdx.x, bh = blockIdx.y;
    const int b = bh >> 3, h = bh & 7;
    const int t = threadIdx.x;
    const u16* src = QKV + ((size_t)(b * Ss + st * 64)) * NQKV + 2 * Cc + h * Dd;
    for (int i = t; i < 640; i += 256) {
        int r = i / 10, c = i % 10;
        short8 v = *(const short8*)(src + (size_t)r * NQKV + c * 8);
#pragma unroll
        for (int j = 0; j < 8; j++) T[c * 8 + j][r] = (u16)v[j];
    }
    __syncthreads();
    u16* dst = VTg + ((size_t)bh * Dd) * Ss + st * 64;
    for (int i = t; i < 640; i += 256) {
        int d = i / 8, c = i % 8;
        short8 v = *(const short8*)&T[d][c * 8];
        *(short8*)(dst + (size_t)d * Ss + c * 8) = v;
    }
}

// ---------------------------------------------------------------------------
// Kernel C: flash attention, 32x32x16 MFMA, swapped operands (S^T, O^T).
// Grid (32 qt, 16 bh, 2 kv-splits); block = 128 q-rows, 4 waves x 32 q.
// K/V staged via global_load_lds into chunk-major LDS, double-buffered,
// ONE barrier per tile. Softmax lane-local; P in registers (permlane swap).
// Outputs: un-normalized numerator (bf16) + m,l per q; merged later.
// ---------------------------------------------------------------------------
constexpr int OBP = 88;

__global__ __launch_bounds__(256, 4) void attn_kernel(
    const u16* __restrict__ QKV, const u16* __restrict__ VTg,
    u16* __restrict__ N0, u16* __restrict__ N1,
    float* __restrict__ Mp, float* __restrict__ Lp)
{
    // [0,20480): K buffers 2 x [10 chunks][64 kv][16B]
    // [20480,40960): V buffers 2 x [80 d][8 chunks][16B] (chunk XOR-swizzled)
    __shared__ __align__(16) char smem[40960];

    const int qt = blockIdx.x;
    const int bh = blockIdx.y;
    const int kvs = blockIdx.z;
    const int b = bh >> 3, h = bh & 7;
    const int t = threadIdx.x, lane = t & 63, w = t >> 6;
    const int l31 = lane & 31, e = lane >> 5;

    const size_t rowBase = (size_t)b * Ss;
    const int q0 = qt * 128;
    const int kvBase = kvs * (Ss / 2);
    constexpr int NT = (Ss / 2) / 64;   // 32

    const int lq8 = lane >> 3;          // 0..7
    const int vcg = (lane & 7) ^ lq8;   // XOR-swizzled global chunk for V stage
    const u16* kg0 = QKV + (rowBase + kvBase + lane) * NQKV + Cc + h * Dd;
    const u16* vg0 = VTg + ((size_t)bh * Dd) * Ss + kvBase + vcg * 8;

    // Q fragments (B-operand: col = q = l31, k-elems at e*8)
    short8 qB[5];
    {
        const u16* qp = QKV + (rowBase + q0 + w * 32 + l31) * NQKV + h * Dd + e * 8;
#pragma unroll
        for (int ks = 0; ks < 5; ks++) qB[ks] = *(const short8*)(qp + ks * 16);
    }

    auto stage = [&](int kt, int bf) {
#pragma unroll
        for (int j = 0; j < 3; j++) {
            int gi = w + 4 * j;
            if (gi < 10) {
                GLD16(kg0 + (size_t)kt * 64 * NQKV + gi * 8,
                      smem + bf * 10240 + gi * 1024);
                GLD16(vg0 + (size_t)(gi * 8 + lq8) * Ss + kt * 64,
                      smem + 20480 + bf * 10240 + gi * 1024);
            }
        }
    };

    stage(0, 0);
    __syncthreads();   // vmcnt drain -> tile 0 in LDS

    float mrow = -1e30f, lrow = 0.f;
    f32x16 oacc[3] = {};
    int cur = 0;
    const int csl_base = l31 & 7;

    for (int kt = 0; kt < NT; ++kt) {
        if (kt + 1 < NT) stage(kt + 1, cur ^ 1);

        const char* kbase = smem + cur * 10240;
        const char* vbase = smem + 20480 + cur * 10240;

        // S^T[kv][q] = K Q^T
        f32x16 s2[2];
#pragma unroll
        for (int n = 0; n < 2; n++) {
            f32x16 a = {};
#pragma unroll
            for (int ks = 0; ks < 5; ks++) {
                short8 kf = *(const short8*)(kbase + ((2 * ks + e) * 64 + n * 32 + l31) * 16);
                a = __builtin_amdgcn_mfma_f32_32x32x16_bf16(kf, qB[ks], a, 0, 0, 0);
            }
            s2[n] = a;
        }

        // lane-local softmax (log2 domain)
        float tm[16];
#pragma unroll
        for (int i = 0; i < 16; i++) tm[i] = fmaxf(s2[0][i], s2[1][i]);
#pragma unroll
        for (int st = 8; st >= 1; st >>= 1)
#pragma unroll
            for (int i = 0; i < st; i++) tm[i] = fmaxf(tm[i], tm[i + st]);
        float vm = tm[0];
        { float va = vm, vb = vm; pswapf(va, vb); vm = fmaxf(va, vb); }

        if (__any(vm > mrow)) {   // exact skip: alpha==1 when no growth
            float mnew = fmaxf(mrow, vm);
            float al = __builtin_amdgcn_exp2f(mrow - mnew);
            mrow = mnew;
            lrow *= al;
#pragma unroll
            for (int n = 0; n < 3; n++)
#pragma unroll
                for (int r = 0; r < 16; r++) oacc[n][r] *= al;
        }

        u32 pd[2][8];
        float ts = 0.f;
#pragma unroll
        for (int n = 0; n < 2; n++)
#pragma unroll
            for (int m = 0; m < 8; m++) {
                float pa = __builtin_amdgcn_exp2f(s2[n][2 * m] - mrow);
                float pb = __builtin_amdgcn_exp2f(s2[n][2 * m + 1] - mrow);
                ts += pa + pb;
                pd[n][m] = packbf2(pa, pb);
            }
        { float ta = ts, tb = ts; pswapf(ta, tb); ts = ta + tb; }
        lrow += ts;

        // PV: O^T[d][q] += V^T[d][kv] * P^T[kv][q]
#pragma unroll
        for (int ks = 0; ks < 4; ks++) {
            const int n = ks >> 1, bb2 = ks & 1;
            u32 x0 = pd[n][4 * bb2 + 0], x1 = pd[n][4 * bb2 + 1];
            u32 x2 = pd[n][4 * bb2 + 2], x3 = pd[n][4 * bb2 + 3];
            pswap2(x0, x2); pswap2(x1, x3);
            union { u32 u[4]; short8 v; } pB;
            pB.u[0] = x0; pB.u[1] = x1; pB.u[2] = x2; pB.u[3] = x3;
            const int csl = (2 * ks + e) ^ csl_base;
#pragma unroll
            for (int n2 = 0; n2 < 3; n2++) {
                short8 vf = *(const short8*)(vbase + ((n2 * 32 + l31) * 8 + csl) * 16);
                oacc[n2] = __builtin_amdgcn_mfma_f32_32x32x16_bf16(vf, pB.v, oacc[n2], 0, 0, 0);
            }
        }

        __syncthreads();  // all waves done with buf cur; next tile (vmcnt) landed
        cur ^= 1;
    }

    // m,l per q (both half-lanes hold identical values; e==0 writes)
    if (e == 0) {
        int mi = kvs * 65536 + bh * Ss + q0 + w * 32 + l31;
        Mp[mi] = mrow;
        Lp[mi] = lrow;
    }

    // pack numerator O^T -> Ob overlay, then coalesced dump
    u16* Ob = (u16*)smem;
#pragma unroll
    for (int n = 0; n < 3; n++)
#pragma unroll
        for (int r = 0; r < 16; r += 2) {
            if (n == 2 && r >= 8) continue;   // d >= 80
            int dloc = n * 32 + (r & 3) + 8 * (r >> 2) + 4 * e;
            u32 pk = packbf2(oacc[n][r], oacc[n][r + 1]);
            *(u32*)&Ob[(w * 32 + l31) * OBP + dloc] = pk;
        }
    __syncthreads();

    u16* Np = kvs ? N1 : N0;
    const int NS = kvs ? NQKV : Cc;
    const int cb = h * Dd;
#pragma unroll
    for (int i = 0; i < 5; i++) {
        int gidx = i * 256 + t;
        int row = gidx / 10, gi = gidx % 10;
        short8 v = *(const short8*)&Ob[row * OBP + gi * 8];
        *(short8*)(Np + (rowBase + q0 + row) * NS + cb + gi * 8) = v;
    }
}

// ---------------------------------------------------------------------------
// Kernel C2: merge the two kv-split partials -> AOb (bf16, [8192][640])
// ---------------------------------------------------------------------------
__global__ __launch_bounds__(256) void merge_kernel(
    const u16* __restrict__ N0, const u16* __restrict__ N1,
    const float* __restrict__ Mp, const float* __restrict__ Lp,
    u16* __restrict__ AOb)
{
    int idx8 = blockIdx.x * 256 + threadIdx.x;   // 0..655359
    int row = idx8 / 80;                          // b*4096 + q
    int c8 = idx8 - row * 80;                     // 0..79
    int h = c8 / 10;
    int bq = row;
    int bb = row >> 12, q = row & 4095;
    int mi = (bb * 8 + h) * Ss + q;
    float m0 = Mp[mi], m1 = Mp[65536 + mi];
    float l0 = Lp[mi], l1 = Lp[65536 + mi];
    float m = fmaxf(m0, m1);
    float w0 = exp2f(m0 - m), w1 = exp2f(m1 - m);
    float rl = 1.0f / (l0 * w0 + l1 * w1);
    w0 *= rl; w1 *= rl;
    const short8 a = *(const short8*)(N0 + (size_t)bq * Cc + c8 * 8);
    const short8 c = *(const short8*)(N1 + (size_t)bq * NQKV + c8 * 8);
    short8 o;
#pragma unroll
    for (int j = 0; j < 8; j++)
        o[j] = (short)f2bf(bf2f((u16)a[j]) * w0 + bf2f((u16)c[j]) * w1);
    *(short8*)(AOb + (size_t)bq * Cc + c8 * 8) = o;
}

// ---------------------------------------------------------------------------
// Kernel D: O-projection + bias + residual, fp32 out.
// ---------------------------------------------------------------------------
__global__ __launch_bounds__(256) void gemm_oproj(
    const u16* __restrict__ A, const u16* __restrict__ Bt,
    const float* __restrict__ bias, const float* __restrict__ resid,
    float* __restrict__ Out, int K)
{
    constexpr int BKP = 40;
    __shared__ __align__(16) u16 As[128 * BKP];
    __shared__ __align__(16) u16 Bs[128 * BKP];

    const int mBase = blockIdx.x * 128;
    const int nBase = blockIdx.y * 128;
    const int t = threadIdx.x, lane = t & 63, w = t >> 6;
    const int wr = w >> 1, wc = w & 1;
    const int l15 = lane & 15, g = lane >> 4;

    f32x4 acc[4][4] = {};
    const int rowA = t >> 1;
    const int colA = (t & 1) * 16;

    for (int k0 = 0; k0 < K; k0 += 32) {
        const u16* pa = A + (size_t)(mBase + rowA) * K + k0 + colA;
        const u16* pb = Bt + (size_t)(nBase + rowA) * K + k0 + colA;
        short8 a0 = *(const short8*)pa;
        short8 a1 = *(const short8*)(pa + 8);
        short8 b0 = *(const short8*)pb;
        short8 b1 = *(const short8*)(pb + 8);
        *(short8*)&As[rowA * BKP + colA] = a0;
        *(short8*)&As[rowA * BKP + colA + 8] = a1;
        *(short8*)&Bs[rowA * BKP + colA] = b0;
        *(short8*)&Bs[rowA * BKP + colA + 8] = b1;
        __syncthreads();
        short8 af[4], bf[4];
#pragma unroll
        for (int i = 0; i < 4; i++) {
            af[i] = *(const short8*)&As[(wr * 64 + i * 16 + l15) * BKP + g * 8];
            bf[i] = *(const short8*)&Bs[(wc * 64 + i * 16 + l15) * BKP + g * 8];
        }
#pragma unroll
        for (int mi = 0; mi < 4; mi++)
#pragma unroll
            for (int ni = 0; ni < 4; ni++)
                acc[mi][ni] = __builtin_amdgcn_mfma_f32_16x16x32_bf16(af[mi], bf[ni], acc[mi][ni], 0, 0, 0);
        __syncthreads();
    }

#pragma unroll
    for (int mi = 0; mi < 4; mi++)
#pragma unroll
        for (int ni = 0; ni < 4; ni++) {
            int col = nBase + wc * 64 + ni * 16 + l15;
            float bb = bias[col];
#pragma unroll
            for (int r = 0; r < 4; r++) {
                int row = mBase + wr * 64 + mi * 16 + g * 4 + r;
                Out[(size_t)row * Cc + col] = acc[mi][ni][r] + bb + resid[(size_t)row * Cc + col];
            }
        }
}

// ---------------------------------------------------------------------------
extern "C" void kernel_launch(void* const* d_in, const int* in_sizes, int n_in,
                              void* d_out, int out_size, void* d_ws, size_t ws_size,
                              hipStream_t stream) {
    (void)in_sizes; (void)n_in; (void)out_size; (void)ws_size;
    const float* hs = (const float*)d_in[0];
    const float* Wq = (const float*)d_in[1];
    const float* bq = (const float*)d_in[2];
    const float* Wk = (const float*)d_in[3];
    const float* bk = (const float*)d_in[4];
    const float* Wv = (const float*)d_in[5];
    const float* bv = (const float*)d_in[6];
    const float* Wo = (const float*)d_in[7];
    const float* bo = (const float*)d_in[8];
    float* out = (float*)d_out;

    char* ws = (char*)d_ws;
    u16*   Xb    = (u16*)  (ws + 0);          // 8192*640*2   = 10,485,760 (reused as VTg)
    u16*   WTqkv = (u16*)  (ws + 10485760);   // 1920*640*2   =  2,457,600
    u16*   WTo   = (u16*)  (ws + 12943360);   // 640*640*2    =    819,200
    float* bcat  = (float*)(ws + 13762560);   // 1920*4       =      7,680
    u16*   QKV   = (u16*)  (ws + 13770240);   // 8192*1920*2  = 31,457,280
    u16*   AOb   = (u16*)  (ws + 45227520);   // 8192*640*2   = 10,485,760 (N0, then merged)
    float* Mp    = (float*)(ws + 55713280);   // 2*16*4096*4  =    524,288
    float* Lp    = (float*)(ws + 56237568);   // 2*16*4096*4  =    524,288
    u16*   VTg   = Xb;                        // overlay: Xb dead after gemm_bf16
    u16*   N1    = QKV + 2 * Cc;              // overlay: V-cols of QKV dead after vtrans

    convert_kernel<<<dim3(2048), dim3(256), 0, stream>>>(hs, Wq, Wk, Wv, Wo, bq, bk, bv,
                                                         Xb, WTqkv, WTo, bcat);
    gemm_bf16<NQKV><<<dim3(64, 15), dim3(256), 0, stream>>>(Xb, WTqkv, bcat, QKV, Cc);
    vtrans_kernel<<<dim3(64, 16), dim3(256), 0, stream>>>(QKV, VTg);
    attn_kernel<<<dim3(32, 16, 2), dim3(256), 0, stream>>>(QKV, VTg, AOb, N1, Mp, Lp);
    merge_kernel<<<dim3(2560), dim3(256), 0, stream>>>(AOb, N1, Mp, Lp, AOb);
    gemm_oproj<<<dim3(64, 5), dim3(256), 0, stream>>>(AOb, WTo, bo, hs, out, Cc);
}

// Round 6
// 224.550 us; speedup vs baseline: 2.6005x; 1.0537x over previous
//
#include <hip/hip_runtime.h>
#include <hip/hip_bf16.h>
#include <stdint.h>

typedef __attribute__((ext_vector_type(8))) short short8;
typedef __attribute__((ext_vector_type(4))) short short4v;
typedef __attribute__((ext_vector_type(2))) float f32x2;
typedef __attribute__((ext_vector_type(4))) float f32x4;
typedef __attribute__((ext_vector_type(16))) float f32x16;
typedef unsigned short u16;
typedef unsigned int u32;

#define DEV __device__ __forceinline__

constexpr int Bb = 2, Ss = 4096, Cc = 640, Hh = 8, Dd = 80;
constexpr int BS = Bb * Ss;          // 8192
constexpr int NQKV = 3 * Cc;         // 1920

DEV float bf2f(u16 u) { unsigned v = ((unsigned)u) << 16; float f; __builtin_memcpy(&f, &v, 4); return f; }
DEV u16 f2bf(float f) {
    unsigned u; __builtin_memcpy(&u, &f, 4);
    u += 0x7fffu + ((u >> 16) & 1u);
    return (u16)(u >> 16);
}
DEV u32 packbf2(float a, float b) {
    float2 f2; f2.x = a; f2.y = b;
    __hip_bfloat162 h2 = __float22bfloat162_rn(f2);
    u32 r; __builtin_memcpy(&r, &h2, 4);
    return r;
}

// permlane32_swap: a' = lane<32 ? a : b[l-32];  b' = lane<32 ? a[l+32] : b
DEV void pswapf(float &a, float &b) {
#if __has_builtin(__builtin_amdgcn_permlane32_swap)
    auto r = __builtin_amdgcn_permlane32_swap(__float_as_int(a), __float_as_int(b), false, false);
    a = __int_as_float(r[0]); b = __int_as_float(r[1]);
#else
    float sa = __shfl_xor(a, 32, 64), sb = __shfl_xor(b, 32, 64);
    bool hi = (threadIdx.x & 32) != 0;
    float na = hi ? sb : a, nb = hi ? b : sa;
    a = na; b = nb;
#endif
}
DEV void pswap2(u32 &a, u32 &b) {
#if __has_builtin(__builtin_amdgcn_permlane32_swap)
    auto r = __builtin_amdgcn_permlane32_swap((int)a, (int)b, false, false);
    a = (u32)r[0]; b = (u32)r[1];
#else
    u32 sa = (u32)__shfl_xor((int)a, 32, 64), sb = (u32)__shfl_xor((int)b, 32, 64);
    bool hi = (threadIdx.x & 32) != 0;
    u32 na = hi ? sb : a, nb = hi ? b : sa;
    a = na; b = nb;
#endif
}

#define GLD16(gp, lp) __builtin_amdgcn_global_load_lds( \
    (const __attribute__((address_space(1))) void*)(gp), \
    (__attribute__((address_space(3))) void*)(lp), 16, 0, 0)

// ---------------------------------------------------------------------------
// Kernel A: hs -> bf16 (vectorized), concat bias. (weights moved to wtrans)
// ---------------------------------------------------------------------------
__global__ void convert_kernel(const float* __restrict__ hs,
                               const float* __restrict__ bq, const float* __restrict__ bk,
                               const float* __restrict__ bv,
                               u16* __restrict__ Xb, float* __restrict__ bcat)
{
    const float QS = 0.11180339887498949f * 1.4426950408889634f;
    int tid = blockIdx.x * blockDim.x + threadIdx.x;
    int nthr = gridDim.x * blockDim.x;
    for (int i = tid; i < BS * Cc / 4; i += nthr) {
        float4 v = ((const float4*)hs)[i];
        short4v o;
        o[0] = (short)f2bf(v.x); o[1] = (short)f2bf(v.y);
        o[2] = (short)f2bf(v.z); o[3] = (short)f2bf(v.w);
        ((short4v*)Xb)[i] = o;
    }
    for (int i = tid; i < NQKV; i += nthr) {
        float v = (i < Cc) ? bq[i] * QS : (i < 2 * Cc) ? bk[i - Cc] : bv[i - 2 * Cc];
        bcat[i] = v;
    }
}

// ---------------------------------------------------------------------------
// Kernel A2: weight transpose via LDS tiles, coalesced both sides.
// WTqkv[n][k] (n<640: Wq*QS; n<1280: Wk; else Wv), WTo[n][k] = Wo[k][n].
// ---------------------------------------------------------------------------
__global__ __launch_bounds__(256) void wtrans_kernel(
    const float* __restrict__ Wq, const float* __restrict__ Wk,
    const float* __restrict__ Wv, const float* __restrict__ Wo,
    u16* __restrict__ WTqkv, u16* __restrict__ WTo)
{
    __shared__ float T[32][33];
    const float QS = 0.11180339887498949f * 1.4426950408889634f;
    int tile = blockIdx.x;            // 4 * 20 * 20
    int wsel = tile / 400;
    int tt = tile - wsel * 400;
    int tr = tt / 20, tc = tt - (tt / 20) * 20;   // tr: k-tile, tc: n-tile
    const float* W = (wsel == 0) ? Wq : (wsel == 1) ? Wk : (wsel == 2) ? Wv : Wo;
    float sc = (wsel == 0) ? QS : 1.0f;
    int r = threadIdx.x >> 3, c4 = (threadIdx.x & 7) * 4;
    float4 v = *(const float4*)(W + (size_t)(tr * 32 + r) * Cc + tc * 32 + c4);
    T[r][c4 + 0] = v.x; T[r][c4 + 1] = v.y; T[r][c4 + 2] = v.z; T[r][c4 + 3] = v.w;
    __syncthreads();
    short4v o;
#pragma unroll
    for (int j = 0; j < 4; j++) o[j] = (short)f2bf(T[c4 + j][r] * sc);
    u16* dst = (wsel < 3) ? (WTqkv + (size_t)(wsel * Cc + tc * 32 + r) * Cc + tr * 32 + c4)
                          : (WTo + (size_t)(tc * 32 + r) * Cc + tr * 32 + c4);
    *(short4v*)dst = o;
}

// ---------------------------------------------------------------------------
// Kernel B: bf16 GEMM  Out[m][n] = sum_k A[m][k] * Bt[n][k] + bias[n]
// ---------------------------------------------------------------------------
template <int N_TOTAL>
__global__ __launch_bounds__(256) void gemm_bf16(
    const u16* __restrict__ A, const u16* __restrict__ Bt,
    const float* __restrict__ bias, u16* __restrict__ Out, int K)
{
    constexpr int BKP = 40;
    __shared__ __align__(16) u16 As[128 * BKP];
    __shared__ __align__(16) u16 Bs[128 * BKP];

    const int mBase = blockIdx.x * 128;
    const int nBase = blockIdx.y * 128;
    const int t = threadIdx.x, lane = t & 63, w = t >> 6;
    const int wr = w >> 1, wc = w & 1;
    const int l15 = lane & 15, g = lane >> 4;

    f32x4 acc[4][4] = {};
    const int rowA = t >> 1;
    const int colA = (t & 1) * 16;

    for (int k0 = 0; k0 < K; k0 += 32) {
        const u16* pa = A + (size_t)(mBase + rowA) * K + k0 + colA;
        const u16* pb = Bt + (size_t)(nBase + rowA) * K + k0 + colA;
        short8 a0 = *(const short8*)pa;
        short8 a1 = *(const short8*)(pa + 8);
        short8 b0 = *(const short8*)pb;
        short8 b1 = *(const short8*)(pb + 8);
        *(short8*)&As[rowA * BKP + colA] = a0;
        *(short8*)&As[rowA * BKP + colA + 8] = a1;
        *(short8*)&Bs[rowA * BKP + colA] = b0;
        *(short8*)&Bs[rowA * BKP + colA + 8] = b1;
        __syncthreads();
        short8 af[4], bf[4];
#pragma unroll
        for (int i = 0; i < 4; i++) {
            af[i] = *(const short8*)&As[(wr * 64 + i * 16 + l15) * BKP + g * 8];
            bf[i] = *(const short8*)&Bs[(wc * 64 + i * 16 + l15) * BKP + g * 8];
        }
#pragma unroll
        for (int mi = 0; mi < 4; mi++)
#pragma unroll
            for (int ni = 0; ni < 4; ni++)
                acc[mi][ni] = __builtin_amdgcn_mfma_f32_16x16x32_bf16(af[mi], bf[ni], acc[mi][ni], 0, 0, 0);
        __syncthreads();
    }

#pragma unroll
    for (int mi = 0; mi < 4; mi++)
#pragma unroll
        for (int ni = 0; ni < 4; ni++) {
            int col = nBase + wc * 64 + ni * 16 + l15;
            float bb = bias[col];
#pragma unroll
            for (int r = 0; r < 4; r++) {
                int row = mBase + wr * 64 + mi * 16 + g * 4 + r;
                Out[(size_t)row * N_TOTAL + col] = f2bf(acc[mi][ni][r] + bb);
            }
        }
}

// ---------------------------------------------------------------------------
// Kernel B2: transpose V part of QKV -> VTg[b*8+h][d][s]  ([16][80][4096] bf16)
// ---------------------------------------------------------------------------
__global__ __launch_bounds__(256) void vtrans_kernel(const u16* __restrict__ QKV,
                                                     u16* __restrict__ VTg)
{
    __shared__ __align__(16) u16 T[80][72];
    const int st = blockIdx.x, bh = blockIdx.y;
    const int b = bh >> 3, h = bh & 7;
    const int t = threadIdx.x;
    const u16* src = QKV + ((size_t)(b * Ss + st * 64)) * NQKV + 2 * Cc + h * Dd;
    for (int i = t; i < 640; i += 256) {
        int r = i / 10, c = i % 10;
        short8 v = *(const short8*)(src + (size_t)r * NQKV + c * 8);
#pragma unroll
        for (int j = 0; j < 8; j++) T[c * 8 + j][r] = (u16)v[j];
    }
    __syncthreads();
    u16* dst = VTg + ((size_t)bh * Dd) * Ss + st * 64;
    for (int i = t; i < 640; i += 256) {
        int d = i / 8, c = i % 8;
        short8 v = *(const short8*)&T[d][c * 8];
        *(short8*)(dst + (size_t)d * Ss + c * 8) = v;
    }
}

// ---------------------------------------------------------------------------
// Kernel C: flash attention, 32x32x16 MFMA, swapped operands (S^T, O^T).
// Grid (32 qt, 16 bh, 2 kv-splits); 4 waves x 32 q. gload_lds double-buffer,
// one barrier/tile. Lane-local softmax: max3 tree + defer-max(8) + pk-adds.
// ---------------------------------------------------------------------------
constexpr int OBP = 88;

__global__ __launch_bounds__(256, 4) void attn_kernel(
    const u16* __restrict__ QKV, const u16* __restrict__ VTg,
    u16* __restrict__ N0, u16* __restrict__ N1,
    float* __restrict__ Mp, float* __restrict__ Lp)
{
    // [0,20480): K bufs 2 x [10 chunks][64 kv][16B]
    // [20480,40960): V bufs 2 x [80 d][8 chunks][16B] (chunk XOR-swizzled)
    __shared__ __align__(16) char smem[40960];

    const int qt = blockIdx.x;
    const int bh = blockIdx.y;
    const int kvs = blockIdx.z;
    const int b = bh >> 3, h = bh & 7;
    const int t = threadIdx.x, lane = t & 63, w = t >> 6;
    const int l31 = lane & 31, e = lane >> 5;

    const size_t rowBase = (size_t)b * Ss;
    const int q0 = qt * 128;
    const int kvBase = kvs * (Ss / 2);
    constexpr int NT = (Ss / 2) / 64;   // 32

    const int lq8 = lane >> 3;
    const int vcg = (lane & 7) ^ lq8;   // XOR-swizzled global chunk for V stage
    const u16* kg0 = QKV + (rowBase + kvBase + lane) * NQKV + Cc + h * Dd;
    const u16* vg0 = VTg + ((size_t)bh * Dd) * Ss + kvBase + vcg * 8;

    // Q fragments (B-operand: col = q = l31, k-elems at e*8)
    short8 qB[5];
    {
        const u16* qp = QKV + (rowBase + q0 + w * 32 + l31) * NQKV + h * Dd + e * 8;
#pragma unroll
        for (int ks = 0; ks < 5; ks++) qB[ks] = *(const short8*)(qp + ks * 16);
    }

    auto stage = [&](int kt, int bf) {
#pragma unroll
        for (int j = 0; j < 3; j++) {
            int gi = w + 4 * j;
            if (gi < 10) {
                GLD16(kg0 + (size_t)kt * 64 * NQKV + gi * 8,
                      smem + bf * 10240 + gi * 1024);
                GLD16(vg0 + (size_t)(gi * 8 + lq8) * Ss + kt * 64,
                      smem + 20480 + bf * 10240 + gi * 1024);
            }
        }
    };

    stage(0, 0);
    __syncthreads();

    float mrow = -1e30f, lrow = 0.f;
    f32x16 oacc[3] = {};
    int cur = 0;
    const int csl_base = l31 & 7;
    const int vr2 = 64 + (l31 & 15);   // n2==2 clamp: lanes l31>=16 duplicate rows
                                       // 64..79 (their D-rows d>=80 are discarded)

    for (int kt = 0; kt < NT; ++kt) {
        if (kt + 1 < NT) stage(kt + 1, cur ^ 1);

        const char* kbase = smem + cur * 10240;
        const char* vbase = smem + 20480 + cur * 10240;

        // S^T[kv][q] = K Q^T
        f32x16 s2[2];
#pragma unroll
        for (int n = 0; n < 2; n++) {
            f32x16 a = {};
#pragma unroll
            for (int ks = 0; ks < 5; ks++) {
                short8 kf = *(const short8*)(kbase + ((2 * ks + e) * 64 + n * 32 + l31) * 16);
                a = __builtin_amdgcn_mfma_f32_32x32x16_bf16(kf, qB[ks], a, 0, 0, 0);
            }
            s2[n] = a;
        }

        // max over 32 scores via max3-friendly triples
#define SV(j) ((j) < 16 ? s2[0][(j)] : s2[1][(j) - 16])
        float tt[11];
#pragma unroll
        for (int i = 0; i < 10; i++)
            tt[i] = fmaxf(fmaxf(SV(3 * i), SV(3 * i + 1)), SV(3 * i + 2));
        tt[10] = fmaxf(SV(30), SV(31));
#undef SV
        float u0 = fmaxf(fmaxf(tt[0], tt[1]), tt[2]);
        float u1 = fmaxf(fmaxf(tt[3], tt[4]), tt[5]);
        float u2 = fmaxf(fmaxf(tt[6], tt[7]), tt[8]);
        float u3 = fmaxf(tt[9], tt[10]);
        float vm = fmaxf(fmaxf(u0, u1), fmaxf(u2, u3));
        { float va = vm, vb = vm; pswapf(va, vb); vm = fmaxf(va, vb); }

        // defer-max (T13): rescale only when max grows by > 8 (log2 domain)
        if (__any(vm > mrow + 8.0f)) {
            float mnew = fmaxf(mrow, vm);
            float al = __builtin_amdgcn_exp2f(mrow - mnew);
            mrow = mnew;
            lrow *= al;
#pragma unroll
            for (int n = 0; n < 3; n++)
#pragma unroll
                for (int r = 0; r < 16; r++) oacc[n][r] *= al;
        }

        u32 pd[2][8];
        f32x2 tsv = {0.f, 0.f};
#pragma unroll
        for (int n = 0; n < 2; n++)
#pragma unroll
            for (int m = 0; m < 8; m++) {
                float pa = __builtin_amdgcn_exp2f(s2[n][2 * m] - mrow);
                float pb = __builtin_amdgcn_exp2f(s2[n][2 * m + 1] - mrow);
                f32x2 pp; pp[0] = pa; pp[1] = pb;
                tsv += pp;                       // v_pk_add_f32
                pd[n][m] = packbf2(pa, pb);
            }
        float ts = tsv[0] + tsv[1];
        { float ta = ts, tb = ts; pswapf(ta, tb); ts = ta + tb; }
        lrow += ts;

        // PV: O^T[d][q] += V^T[d][kv] * P^T[kv][q]
#pragma unroll
        for (int ks = 0; ks < 4; ks++) {
            const int n = ks >> 1, bb2 = ks & 1;
            u32 x0 = pd[n][4 * bb2 + 0], x1 = pd[n][4 * bb2 + 1];
            u32 x2 = pd[n][4 * bb2 + 2], x3 = pd[n][4 * bb2 + 3];
            pswap2(x0, x2); pswap2(x1, x3);
            union { u32 u[4]; short8 v; } pB;
            pB.u[0] = x0; pB.u[1] = x1; pB.u[2] = x2; pB.u[3] = x3;
            const int csl = (2 * ks + e) ^ csl_base;
#pragma unroll
            for (int n2 = 0; n2 < 3; n2++) {
                const int arow = (n2 == 2) ? vr2 : (n2 * 32 + l31);
                short8 vf = *(const short8*)(vbase + (arow * 8 + csl) * 16);
                oacc[n2] = __builtin_amdgcn_mfma_f32_32x32x16_bf16(vf, pB.v, oacc[n2], 0, 0, 0);
            }
        }

        __syncthreads();  // all waves done with buf cur; next tile landed
        cur ^= 1;
    }

    if (e == 0) {
        int mi = kvs * 65536 + bh * Ss + q0 + w * 32 + l31;
        Mp[mi] = mrow;
        Lp[mi] = lrow;
    }

    // pack numerator O^T -> Ob overlay, then coalesced dump
    u16* Ob = (u16*)smem;
#pragma unroll
    for (int n = 0; n < 3; n++)
#pragma unroll
        for (int r = 0; r < 16; r += 2) {
            if (n == 2 && r >= 8) continue;   // d >= 80
            int dloc = n * 32 + (r & 3) + 8 * (r >> 2) + 4 * e;
            u32 pk = packbf2(oacc[n][r], oacc[n][r + 1]);
            *(u32*)&Ob[(w * 32 + l31) * OBP + dloc] = pk;
        }
    __syncthreads();

    u16* Np = kvs ? N1 : N0;
    const int NS = kvs ? NQKV : Cc;
    const int cb = h * Dd;
#pragma unroll
    for (int i = 0; i < 5; i++) {
        int gidx = i * 256 + t;
        int row = gidx / 10, gi = gidx % 10;
        short8 v = *(const short8*)&Ob[row * OBP + gi * 8];
        *(short8*)(Np + (rowBase + q0 + row) * NS + cb + gi * 8) = v;
    }
}

// ---------------------------------------------------------------------------
// Kernel C2: merge the two kv-split partials -> AOb (bf16, [8192][640])
// ---------------------------------------------------------------------------
__global__ __launch_bounds__(256) void merge_kernel(
    const u16* __restrict__ N0, const u16* __restrict__ N1,
    const float* __restrict__ Mp, const float* __restrict__ Lp,
    u16* __restrict__ AOb)
{
    int idx8 = blockIdx.x * 256 + threadIdx.x;
    int row = idx8 / 80;
    int c8 = idx8 - row * 80;
    int h = c8 / 10;
    int bq = row;
    int bb = row >> 12, q = row & 4095;
    int mi = (bb * 8 + h) * Ss + q;
    float m0 = Mp[mi], m1 = Mp[65536 + mi];
    float l0 = Lp[mi], l1 = Lp[65536 + mi];
    float m = fmaxf(m0, m1);
    float w0 = exp2f(m0 - m), w1 = exp2f(m1 - m);
    float rl = 1.0f / (l0 * w0 + l1 * w1);
    w0 *= rl; w1 *= rl;
    const short8 a = *(const short8*)(N0 + (size_t)bq * Cc + c8 * 8);
    const short8 c = *(const short8*)(N1 + (size_t)bq * NQKV + c8 * 8);
    short8 o;
#pragma unroll
    for (int j = 0; j < 8; j++)
        o[j] = (short)f2bf(bf2f((u16)a[j]) * w0 + bf2f((u16)c[j]) * w1);
    *(short8*)(AOb + (size_t)bq * Cc + c8 * 8) = o;
}

// ---------------------------------------------------------------------------
// Kernel D: O-projection + bias + residual, fp32 out.
// ---------------------------------------------------------------------------
__global__ __launch_bounds__(256) void gemm_oproj(
    const u16* __restrict__ A, const u16* __restrict__ Bt,
    const float* __restrict__ bias, const float* __restrict__ resid,
    float* __restrict__ Out, int K)
{
    constexpr int BKP = 40;
    __shared__ __align__(16) u16 As[128 * BKP];
    __shared__ __align__(16) u16 Bs[128 * BKP];

    const int mBase = blockIdx.x * 128;
    const int nBase = blockIdx.y * 128;
    const int t = threadIdx.x, lane = t & 63, w = t >> 6;
    const int wr = w >> 1, wc = w & 1;
    const int l15 = lane & 15, g = lane >> 4;

    f32x4 acc[4][4] = {};
    const int rowA = t >> 1;
    const int colA = (t & 1) * 16;

    for (int k0 = 0; k0 < K; k0 += 32) {
        const u16* pa = A + (size_t)(mBase + rowA) * K + k0 + colA;
        const u16* pb = Bt + (size_t)(nBase + rowA) * K + k0 + colA;
        short8 a0 = *(const short8*)pa;
        short8 a1 = *(const short8*)(pa + 8);
        short8 b0 = *(const short8*)pb;
        short8 b1 = *(const short8*)(pb + 8);
        *(short8*)&As[rowA * BKP + colA] = a0;
        *(short8*)&As[rowA * BKP + colA + 8] = a1;
        *(short8*)&Bs[rowA * BKP + colA] = b0;
        *(short8*)&Bs[rowA * BKP + colA + 8] = b1;
        __syncthreads();
        short8 af[4], bf[4];
#pragma unroll
        for (int i = 0; i < 4; i++) {
            af[i] = *(const short8*)&As[(wr * 64 + i * 16 + l15) * BKP + g * 8];
            bf[i] = *(const short8*)&Bs[(wc * 64 + i * 16 + l15) * BKP + g * 8];
        }
#pragma unroll
        for (int mi = 0; mi < 4; mi++)
#pragma unroll
            for (int ni = 0; ni < 4; ni++)
                acc[mi][ni] = __builtin_amdgcn_mfma_f32_16x16x32_bf16(af[mi], bf[ni], acc[mi][ni], 0, 0, 0);
        __syncthreads();
    }

#pragma unroll
    for (int mi = 0; mi < 4; mi++)
#pragma unroll
        for (int ni = 0; ni < 4; ni++) {
            int col = nBase + wc * 64 + ni * 16 + l15;
            float bb = bias[col];
#pragma unroll
            for (int r = 0; r < 4; r++) {
                int row = mBase + wr * 64 + mi * 16 + g * 4 + r;
                Out[(size_t)row * Cc + col] = acc[mi][ni][r] + bb + resid[(size_t)row * Cc + col];
            }
        }
}

// ---------------------------------------------------------------------------
extern "C" void kernel_launch(void* const* d_in, const int* in_sizes, int n_in,
                              void* d_out, int out_size, void* d_ws, size_t ws_size,
                              hipStream_t stream) {
    (void)in_sizes; (void)n_in; (void)out_size; (void)ws_size;
    const float* hs = (const float*)d_in[0];
    const float* Wq = (const float*)d_in[1];
    const float* bq = (const float*)d_in[2];
    const float* Wk = (const float*)d_in[3];
    const float* bk = (const float*)d_in[4];
    const float* Wv = (const float*)d_in[5];
    const float* bv = (const float*)d_in[6];
    const float* Wo = (const float*)d_in[7];
    const float* bo = (const float*)d_in[8];
    float* out = (float*)d_out;

    char* ws = (char*)d_ws;
    u16*   Xb    = (u16*)  (ws + 0);          // 8192*640*2   = 10,485,760 (reused as VTg)
    u16*   WTqkv = (u16*)  (ws + 10485760);   // 1920*640*2   =  2,457,600
    u16*   WTo   = (u16*)  (ws + 12943360);   // 640*640*2    =    819,200
    float* bcat  = (float*)(ws + 13762560);   // 1920*4       =      7,680
    u16*   QKV   = (u16*)  (ws + 13770240);   // 8192*1920*2  = 31,457,280
    u16*   AOb   = (u16*)  (ws + 45227520);   // 8192*640*2   = 10,485,760 (N0, then merged)
    float* Mp    = (float*)(ws + 55713280);   // 2*16*4096*4  =    524,288
    float* Lp    = (float*)(ws + 56237568);   // 2*16*4096*4  =    524,288
    u16*   VTg   = Xb;                        // overlay: Xb dead after gemm_bf16
    u16*   N1    = QKV + 2 * Cc;              // overlay: V-cols of QKV dead after vtrans

    convert_kernel<<<dim3(2048), dim3(256), 0, stream>>>(hs, bq, bk, bv, Xb, bcat);
    wtrans_kernel<<<dim3(1600), dim3(256), 0, stream>>>(Wq, Wk, Wv, Wo, WTqkv, WTo);
    gemm_bf16<NQKV><<<dim3(64, 15), dim3(256), 0, stream>>>(Xb, WTqkv, bcat, QKV, Cc);
    vtrans_kernel<<<dim3(64, 16), dim3(256), 0, stream>>>(QKV, VTg);
    attn_kernel<<<dim3(32, 16, 2), dim3(256), 0, stream>>>(QKV, VTg, AOb, N1, Mp, Lp);
    merge_kernel<<<dim3(2560), dim3(256), 0, stream>>>(AOb, N1, Mp, Lp, AOb);
    gemm_oproj<<<dim3(64, 5), dim3(256), 0, stream>>>(AOb, WTo, bo, hs, out, Cc);
}